// Round 3
// baseline (1114.919 us; speedup 1.0000x reference)
//
#include <hip/hip_runtime.h>
#include <math.h>

// GAT 3-layer forward on MI355X.
//   CSR build (histogram -> scan -> scatter by dst)
//   W-prep: split each W into (hi,lo) bf16 and transpose to [n][k]
//   L1..L3: gemm_mfma (3x bf16-split) -> score -> aggregate
// Aggregation: block = node, wave = head; lane-parallel online softmax, no atomics.

#define HEADS 4
#define SLOPE 0.2f

typedef __attribute__((ext_vector_type(4))) float  f32x4;
typedef __attribute__((ext_vector_type(4))) short  short4v;
typedef __attribute__((ext_vector_type(8))) short  short8v;

static inline int cdiv(int a, int b) { return (a + b - 1) / b; }

// fp32 -> bf16 hi (truncate) + bf16 lo (truncate of exact remainder).
// x = hi + lo + err, |err| <= 2^-16 |x|.
__device__ inline void split_bf16(float x, short& hi, short& lo) {
    unsigned b = __float_as_uint(x);
    hi = (short)(b >> 16);
    float hif = __uint_as_float(b & 0xffff0000u);
    float rem = x - hif;  // exact
    lo = (short)(__float_as_uint(rem) >> 16);
}

// ---------------- CSR build ----------------
__global__ void hist_kernel(const int* __restrict__ dst, int* __restrict__ cnt, int E) {
    int i = blockIdx.x * blockDim.x + threadIdx.x;
    if (i < E) atomicAdd(&cnt[dst[i]], 1);
}

__global__ void scan1_kernel(const int* __restrict__ cnt, int* __restrict__ rowStart,
                             int* __restrict__ blockSums, int N) {
    __shared__ int s[256];
    int t = threadIdx.x;
    int i = blockIdx.x * 256 + t;
    int v = (i < N) ? cnt[i] : 0;
    s[t] = v;
    for (int off = 1; off < 256; off <<= 1) {
        __syncthreads();
        int add = (t >= off) ? s[t - off] : 0;
        __syncthreads();
        s[t] += add;
    }
    __syncthreads();
    if (i < N) rowStart[i] = s[t] - v;
    if (t == 255) blockSums[blockIdx.x] = s[255];
}

__global__ void scan2_kernel(int* blockSums, int nb) {
    __shared__ int s[256];
    int t = threadIdx.x;
    int v = (t < nb) ? blockSums[t] : 0;
    s[t] = v;
    for (int off = 1; off < 256; off <<= 1) {
        __syncthreads();
        int add = (t >= off) ? s[t - off] : 0;
        __syncthreads();
        s[t] += add;
    }
    if (t < nb) blockSums[t] = s[t] - v;
}

__global__ void scan3_kernel(int* rowStart, const int* __restrict__ blockSums, int N, int E) {
    int i = blockIdx.x * 256 + threadIdx.x;
    if (i < N) rowStart[i] += blockSums[i >> 8];
    else if (i == N) rowStart[N] = E;
}

__global__ void scatter_kernel(const int* __restrict__ src, const int* __restrict__ dst,
                               const int* __restrict__ rowStart, int* __restrict__ cursor,
                               int* __restrict__ eSrc, int E) {
    int i = blockIdx.x * blockDim.x + threadIdx.x;
    if (i < E) {
        int d = dst[i];
        int pos = rowStart[d] + atomicAdd(&cursor[d], 1);
        eSrc[pos] = src[i];
    }
}

// ---------------- W prep: split + transpose ----------------
// W[K][Nn] fp32 -> hiT[Nn][K], loT[Nn][K] bf16 (k-contiguous rows)
__global__ void wsplit_kernel(const float* __restrict__ W, short* __restrict__ hiT,
                              short* __restrict__ loT, int K, int Nn) {
    int id = blockIdx.x * 256 + threadIdx.x;
    if (id >= K * Nn) return;
    int k = id / Nn, n = id - k * Nn;
    short h, l;
    split_bf16(W[id], h, l);
    hiT[n * K + k] = h;
    loT[n * K + k] = l;
}

// ---------------- MFMA GEMM: C[M,Nn] = A[M,K] @ W[K,Nn] ----------------
// 3x bf16-split (hi*hi + hi*lo + lo*hi), fp32 accumulate.
// Block 256 thr = 4 waves (2x2), tile 128x64, BK=32, mfma_f32_16x16x32_bf16.
// LDS rows padded to 40 halfs (80B): b128 frag reads are bank-uniform.
// Fragment layout: A[m=l&15][k=8*(l>>4)+j]; B[k=8*(l>>4)+j][n=l&15];
// D: col=lane&15, row=(lane>>4)*4+reg (m89-verified).
__global__ __launch_bounds__(256) void gemm_mfma_kernel(
        const float* __restrict__ A, const short* __restrict__ BhiT,
        const short* __restrict__ BloT, float* __restrict__ C,
        int M, int K, int Nn) {
    __shared__ short Ahi[128 * 40];
    __shared__ short Alo[128 * 40];
    __shared__ short Bhi[64 * 40];
    __shared__ short Blo[64 * 40];
    int t = threadIdx.x;
    int lane = t & 63, wid = t >> 6;
    int wr = wid >> 1, wc = wid & 1;   // 2x2 wave grid
    int l15 = lane & 15, g = lane >> 4;
    int row0 = blockIdx.y * 128, col0 = blockIdx.x * 64;

    f32x4 acc[4][2] = {};

    for (int k0 = 0; k0 < K; k0 += 32) {
        // ---- stage A tile 128x32 (fp32 -> hi/lo bf16) ----
#pragma unroll
        for (int i = 0; i < 4; i++) {
            int q = t + i * 256;            // 0..1023 quads
            int r = q >> 3, qc = q & 7;     // row, quad-of-4 within 32 k
            int gr = row0 + r;
            f32x4 v = {};
            if (gr < M) v = *(const f32x4*)(A + (size_t)gr * K + k0 + qc * 4);
            short4v h4, l4;
#pragma unroll
            for (int e = 0; e < 4; e++) {
                short hh, ll;
                split_bf16(v[e], hh, ll);
                h4[e] = hh;
                l4[e] = ll;
            }
            *(short4v*)(Ahi + r * 40 + qc * 4) = h4;
            *(short4v*)(Alo + r * 40 + qc * 4) = l4;
        }
        // ---- stage B tile 64x32 (already bf16, k-contiguous) ----
        {
            int n = t >> 2, kq = t & 3;
            int gc = col0 + n;
            short8v h8 = {}, l8 = {};
            if (gc < Nn) {
                h8 = *(const short8v*)(BhiT + (size_t)gc * K + k0 + kq * 8);
                l8 = *(const short8v*)(BloT + (size_t)gc * K + k0 + kq * 8);
            }
            *(short8v*)(Bhi + n * 40 + kq * 8) = h8;
            *(short8v*)(Blo + n * 40 + kq * 8) = l8;
        }
        __syncthreads();
        // ---- fragments + MFMA ----
        short8v ah[4], al[4], bh[2], bl[2];
#pragma unroll
        for (int mt = 0; mt < 4; mt++) {
            int r = wr * 64 + mt * 16 + l15;
            ah[mt] = *(const short8v*)(Ahi + r * 40 + g * 8);
            al[mt] = *(const short8v*)(Alo + r * 40 + g * 8);
        }
#pragma unroll
        for (int nt = 0; nt < 2; nt++) {
            int n = wc * 32 + nt * 16 + l15;
            bh[nt] = *(const short8v*)(Bhi + n * 40 + g * 8);
            bl[nt] = *(const short8v*)(Blo + n * 40 + g * 8);
        }
#pragma unroll
        for (int mt = 0; mt < 4; mt++)
#pragma unroll
            for (int nt = 0; nt < 2; nt++) {
                acc[mt][nt] = __builtin_amdgcn_mfma_f32_16x16x32_bf16(ah[mt], bh[nt], acc[mt][nt], 0, 0, 0);
                acc[mt][nt] = __builtin_amdgcn_mfma_f32_16x16x32_bf16(ah[mt], bl[nt], acc[mt][nt], 0, 0, 0);
                acc[mt][nt] = __builtin_amdgcn_mfma_f32_16x16x32_bf16(al[mt], bh[nt], acc[mt][nt], 0, 0, 0);
            }
        __syncthreads();
    }
    // ---- C write ----
#pragma unroll
    for (int mt = 0; mt < 4; mt++) {
        int rbase = row0 + wr * 64 + mt * 16 + g * 4;
#pragma unroll
        for (int nt = 0; nt < 2; nt++) {
            int gc = col0 + wc * 32 + nt * 16 + l15;
            if (gc >= Nn) continue;
#pragma unroll
            for (int r = 0; r < 4; r++) {
                int gr = rbase + r;
                if (gr < M) C[(size_t)gr * Nn + gc] = acc[mt][nt][r];
            }
        }
    }
}

// ---------------- attention scores: si/sj [N,H] ----------------
__global__ __launch_bounds__(256) void score_kernel(const float* __restrict__ h,
                                                    const float* __restrict__ attI,
                                                    const float* __restrict__ attJ,
                                                    float* __restrict__ si,
                                                    float* __restrict__ sj, int F) {
    int n = blockIdx.x;
    int hd = threadIdx.x >> 6, lane = threadIdx.x & 63;
    const float* hrow = h + (size_t)n * (HEADS * F) + hd * F;
    float v1 = 0.f, v2 = 0.f;
    for (int f = lane; f < F; f += 64) {
        float xv = hrow[f];
        v1 = fmaf(xv, attI[hd * F + f], v1);
        v2 = fmaf(xv, attJ[hd * F + f], v2);
    }
#pragma unroll
    for (int off = 32; off; off >>= 1) {
        v1 += __shfl_xor(v1, off);
        v2 += __shfl_xor(v2, off);
    }
    if (lane == 0) {
        si[n * HEADS + hd] = v1;
        sj[n * HEADS + hd] = v2;
    }
}

// ---------------- edge softmax + aggregate ----------------
// pass 1: lane-parallel online (max, denom); pass 2: weighted row accumulation.
template <int F, bool ELU_OUT, bool FINAL>
__global__ __launch_bounds__(256) void aggregate_kernel(const float* __restrict__ h,
                                                        const float* __restrict__ si,
                                                        const float* __restrict__ sj,
                                                        const int* __restrict__ rowStart,
                                                        const int* __restrict__ eSrc,
                                                        float* __restrict__ out) {
    int n = blockIdx.x;
    int hd = threadIdx.x >> 6, lane = threadIdx.x & 63;
    int s0 = rowStart[n], s1 = rowStart[n + 1];
    float sin = si[n * HEADS + hd];

    float m = -INFINITY, d = 0.f;
    for (int i = s0 + lane; i < s1; i += 64) {
        int s = eSrc[i];
        float e = sin + sj[s * HEADS + hd];
        e = (e > 0.f) ? e : SLOPE * e;
        float nm = fmaxf(m, e);
        d = d * expf(m - nm) + expf(e - nm);
        m = nm;
    }
#pragma unroll
    for (int off = 32; off; off >>= 1) {
        float om = __shfl_xor(m, off);
        float od = __shfl_xor(d, off);
        float nm = fmaxf(m, om);
        float w1 = (m == -INFINITY) ? 0.f : expf(m - nm);
        float w2 = (om == -INFINITY) ? 0.f : expf(om - nm);
        d = d * w1 + od * w2;
        m = nm;
    }
    float inv = (d > 0.f) ? 1.f / d : 0.f;

    float acc = 0.f;
    for (int i = s0; i < s1; i++) {
        int s = eSrc[i];
        float e = sin + sj[s * HEADS + hd];
        e = (e > 0.f) ? e : SLOPE * e;
        float ex = expf(e - m);
        if (lane < F) acc = fmaf(ex, h[(size_t)s * (HEADS * F) + hd * F + lane], acc);
    }
    float val = acc * inv;
    if (ELU_OUT) val = (val > 0.f) ? val : expm1f(val);

    if (!FINAL) {
        if (lane < F) out[(size_t)n * (HEADS * F) + hd * F + lane] = val;
    } else {
        __shared__ float tmp[HEADS][F];
        if (lane < F) tmp[hd][lane] = val;
        __syncthreads();
        if (hd == 0) {
            float x = (lane < F) ? 0.25f * (tmp[0][lane] + tmp[1][lane] + tmp[2][lane] + tmp[3][lane])
                                 : -INFINITY;
            float mx = x;
#pragma unroll
            for (int off = 32; off; off >>= 1) mx = fmaxf(mx, __shfl_xor(mx, off));
            float ex = (lane < F) ? expf(x - mx) : 0.f;
            float ssum = ex;
#pragma unroll
            for (int off = 32; off; off >>= 1) ssum += __shfl_xor(ssum, off);
            float ls = logf(ssum);
            if (lane < F) out[(size_t)n * F + lane] = (x - mx) - ls;
        }
    }
}

// ---------------- launch ----------------
extern "C" void kernel_launch(void* const* d_in, const int* in_sizes, int n_in,
                              void* d_out, int out_size, void* d_ws, size_t ws_size,
                              hipStream_t stream) {
    const float* x   = (const float*)d_in[0];
    const int*   ei  = (const int*)d_in[1];
    const float* W1  = (const float*)d_in[2];
    const float* ai1 = (const float*)d_in[3];
    const float* aj1 = (const float*)d_in[4];
    const float* W2  = (const float*)d_in[5];
    const float* ai2 = (const float*)d_in[6];
    const float* aj2 = (const float*)d_in[7];
    const float* W3  = (const float*)d_in[8];
    const float* ai3 = (const float*)d_in[9];
    const float* aj3 = (const float*)d_in[10];

    const int IN_F = 256, HID = 64, NCLS = 40;
    const int N = in_sizes[0] / IN_F;   // 50000
    const int E = in_sizes[1] / 2;      // 800000
    const int D1 = HEADS * HID;         // 256
    const int D3 = HEADS * NCLS;        // 160

    const int* eSrcIn = ei;
    const int* eDstIn = ei + E;

    char* p = (char*)d_ws;
    auto carve = [&](size_t bytes) {
        char* r = p;
        p += (bytes + 255) & ~(size_t)255;
        return r;
    };
    float* hA        = (float*)carve((size_t)N * D1 * 4);
    float* hG        = (float*)carve((size_t)N * D1 * 4);
    float* si        = (float*)carve((size_t)N * HEADS * 4);
    float* sj        = (float*)carve((size_t)N * HEADS * 4);
    int*   rowStart  = (int*)carve((size_t)(N + 1) * 4);
    int*   cursor    = (int*)carve((size_t)N * 4);
    int*   eSrc      = (int*)carve((size_t)E * 4);
    int*   blockSums = (int*)carve(1024);
    short* W1hiT     = (short*)carve((size_t)IN_F * D1 * 2);
    short* W1loT     = (short*)carve((size_t)IN_F * D1 * 2);
    short* W2hiT     = (short*)carve((size_t)D1 * D1 * 2);
    short* W2loT     = (short*)carve((size_t)D1 * D1 * 2);
    short* W3hiT     = (short*)carve((size_t)D1 * D3 * 2);
    short* W3loT     = (short*)carve((size_t)D1 * D3 * 2);

    int nbScan = cdiv(N, 256);

    // ---- W prep ----
    wsplit_kernel<<<cdiv(IN_F * D1, 256), 256, 0, stream>>>(W1, W1hiT, W1loT, IN_F, D1);
    wsplit_kernel<<<cdiv(D1 * D1, 256), 256, 0, stream>>>(W2, W2hiT, W2loT, D1, D1);
    wsplit_kernel<<<cdiv(D1 * D3, 256), 256, 0, stream>>>(W3, W3hiT, W3loT, D1, D3);

    // ---- CSR build ----
    hipMemsetAsync(cursor, 0, (size_t)N * 4, stream);
    hist_kernel<<<cdiv(E, 256), 256, 0, stream>>>(eDstIn, cursor, E);
    scan1_kernel<<<nbScan, 256, 0, stream>>>(cursor, rowStart, blockSums, N);
    scan2_kernel<<<1, 256, 0, stream>>>(blockSums, nbScan);
    scan3_kernel<<<cdiv(N + 1, 256), 256, 0, stream>>>(rowStart, blockSums, N, E);
    hipMemsetAsync(cursor, 0, (size_t)N * 4, stream);
    scatter_kernel<<<cdiv(E, 256), 256, 0, stream>>>(eSrcIn, eDstIn, rowStart, cursor, eSrc, E);

    dim3 g1(cdiv(D1, 64), cdiv(N, 128));
    dim3 g3(cdiv(D3, 64), cdiv(N, 128));

    // ---- layer 1 ----
    gemm_mfma_kernel<<<g1, 256, 0, stream>>>(x, W1hiT, W1loT, hG, N, IN_F, D1);
    score_kernel<<<N, 256, 0, stream>>>(hG, ai1, aj1, si, sj, HID);
    aggregate_kernel<64, true, false><<<N, 256, 0, stream>>>(hG, si, sj, rowStart, eSrc, hA);

    // ---- layer 2 ----
    gemm_mfma_kernel<<<g1, 256, 0, stream>>>(hA, W2hiT, W2loT, hG, N, D1, D1);
    score_kernel<<<N, 256, 0, stream>>>(hG, ai2, aj2, si, sj, HID);
    aggregate_kernel<64, true, false><<<N, 256, 0, stream>>>(hG, si, sj, rowStart, eSrc, hA);

    // ---- layer 3 ----
    gemm_mfma_kernel<<<g3, 256, 0, stream>>>(hA, W3hiT, W3loT, hG, N, D1, D3);
    score_kernel<<<N, 256, 0, stream>>>(hG, ai3, aj3, si, sj, NCLS);
    aggregate_kernel<40, false, true><<<N, 256, 0, stream>>>(hG, si, sj, rowStart, eSrc, (float*)d_out);
}

// Round 4
// 791.037 us; speedup vs baseline: 1.4094x; 1.4094x over previous
//
#include <hip/hip_runtime.h>
#include <math.h>

// GAT 3-layer forward on MI355X.
//   CSR build (histogram -> scan -> scatter by dst)
//   W-prep: split each W into (hi,lo) bf16 and transpose to [n][k]
//   L1..L3: gemm_mfma (3x bf16-split, writes fp32 + fp16 copies) -> score -> aggregate
// Aggregate (L1/L2): wave = node (all 4 heads), fp16 gather (512B/edge/wave),
// 16-edge batches with shfl-broadcast indices for deep MLP. No atomics.

#define HEADS 4
#define SLOPE 0.2f

typedef __attribute__((ext_vector_type(4))) float  f32x4;
typedef __attribute__((ext_vector_type(4))) short  short4v;
typedef __attribute__((ext_vector_type(8))) short  short8v;
typedef __attribute__((ext_vector_type(4))) _Float16 half4v;

static inline int cdiv(int a, int b) { return (a + b - 1) / b; }

// fp32 -> bf16 hi (truncate) + bf16 lo (truncate of exact remainder).
__device__ inline void split_bf16(float x, short& hi, short& lo) {
    unsigned b = __float_as_uint(x);
    hi = (short)(b >> 16);
    float hif = __uint_as_float(b & 0xffff0000u);
    float rem = x - hif;  // exact
    lo = (short)(__float_as_uint(rem) >> 16);
}

// ---------------- CSR build ----------------
__global__ void hist_kernel(const int* __restrict__ dst, int* __restrict__ cnt, int E) {
    int i = blockIdx.x * blockDim.x + threadIdx.x;
    if (i < E) atomicAdd(&cnt[dst[i]], 1);
}

__global__ void scan1_kernel(const int* __restrict__ cnt, int* __restrict__ rowStart,
                             int* __restrict__ blockSums, int N) {
    __shared__ int s[256];
    int t = threadIdx.x;
    int i = blockIdx.x * 256 + t;
    int v = (i < N) ? cnt[i] : 0;
    s[t] = v;
    for (int off = 1; off < 256; off <<= 1) {
        __syncthreads();
        int add = (t >= off) ? s[t - off] : 0;
        __syncthreads();
        s[t] += add;
    }
    __syncthreads();
    if (i < N) rowStart[i] = s[t] - v;
    if (t == 255) blockSums[blockIdx.x] = s[255];
}

__global__ void scan2_kernel(int* blockSums, int nb) {
    __shared__ int s[256];
    int t = threadIdx.x;
    int v = (t < nb) ? blockSums[t] : 0;
    s[t] = v;
    for (int off = 1; off < 256; off <<= 1) {
        __syncthreads();
        int add = (t >= off) ? s[t - off] : 0;
        __syncthreads();
        s[t] += add;
    }
    if (t < nb) blockSums[t] = s[t] - v;
}

__global__ void scan3_kernel(int* rowStart, const int* __restrict__ blockSums, int N, int E) {
    int i = blockIdx.x * 256 + threadIdx.x;
    if (i < N) rowStart[i] += blockSums[i >> 8];
    else if (i == N) rowStart[N] = E;
}

__global__ void scatter_kernel(const int* __restrict__ src, const int* __restrict__ dst,
                               const int* __restrict__ rowStart, int* __restrict__ cursor,
                               int* __restrict__ eSrc, int E) {
    int i = blockIdx.x * blockDim.x + threadIdx.x;
    if (i < E) {
        int d = dst[i];
        int pos = rowStart[d] + atomicAdd(&cursor[d], 1);
        eSrc[pos] = src[i];
    }
}

// ---------------- W prep: split + transpose ----------------
__global__ void wsplit_kernel(const float* __restrict__ W, short* __restrict__ hiT,
                              short* __restrict__ loT, int K, int Nn) {
    int id = blockIdx.x * 256 + threadIdx.x;
    if (id >= K * Nn) return;
    int k = id / Nn, n = id - k * Nn;
    short h, l;
    split_bf16(W[id], h, l);
    hiT[n * K + k] = h;
    loT[n * K + k] = l;
}

// ---------------- MFMA GEMM: C[M,Nn] = A[M,K] @ W[K,Nn] ----------------
// 3x bf16-split; writes fp32 C and fp16 copy Ch.
__global__ __launch_bounds__(256) void gemm_mfma_kernel(
        const float* __restrict__ A, const short* __restrict__ BhiT,
        const short* __restrict__ BloT, float* __restrict__ C,
        _Float16* __restrict__ Ch, int M, int K, int Nn) {
    __shared__ short Ahi[128 * 40];
    __shared__ short Alo[128 * 40];
    __shared__ short Bhi[64 * 40];
    __shared__ short Blo[64 * 40];
    int t = threadIdx.x;
    int lane = t & 63, wid = t >> 6;
    int wr = wid >> 1, wc = wid & 1;
    int l15 = lane & 15, g = lane >> 4;
    int row0 = blockIdx.y * 128, col0 = blockIdx.x * 64;

    f32x4 acc[4][2] = {};

    for (int k0 = 0; k0 < K; k0 += 32) {
#pragma unroll
        for (int i = 0; i < 4; i++) {
            int q = t + i * 256;
            int r = q >> 3, qc = q & 7;
            int gr = row0 + r;
            f32x4 v = {};
            if (gr < M) v = *(const f32x4*)(A + (size_t)gr * K + k0 + qc * 4);
            short4v h4, l4;
#pragma unroll
            for (int e = 0; e < 4; e++) {
                short hh, ll;
                split_bf16(v[e], hh, ll);
                h4[e] = hh;
                l4[e] = ll;
            }
            *(short4v*)(Ahi + r * 40 + qc * 4) = h4;
            *(short4v*)(Alo + r * 40 + qc * 4) = l4;
        }
        {
            int n = t >> 2, kq = t & 3;
            int gc = col0 + n;
            short8v h8 = {}, l8 = {};
            if (gc < Nn) {
                h8 = *(const short8v*)(BhiT + (size_t)gc * K + k0 + kq * 8);
                l8 = *(const short8v*)(BloT + (size_t)gc * K + k0 + kq * 8);
            }
            *(short8v*)(Bhi + n * 40 + kq * 8) = h8;
            *(short8v*)(Blo + n * 40 + kq * 8) = l8;
        }
        __syncthreads();
        short8v ah[4], al[4], bh[2], bl[2];
#pragma unroll
        for (int mt = 0; mt < 4; mt++) {
            int r = wr * 64 + mt * 16 + l15;
            ah[mt] = *(const short8v*)(Ahi + r * 40 + g * 8);
            al[mt] = *(const short8v*)(Alo + r * 40 + g * 8);
        }
#pragma unroll
        for (int nt = 0; nt < 2; nt++) {
            int n = wc * 32 + nt * 16 + l15;
            bh[nt] = *(const short8v*)(Bhi + n * 40 + g * 8);
            bl[nt] = *(const short8v*)(Blo + n * 40 + g * 8);
        }
#pragma unroll
        for (int mt = 0; mt < 4; mt++)
#pragma unroll
            for (int nt = 0; nt < 2; nt++) {
                acc[mt][nt] = __builtin_amdgcn_mfma_f32_16x16x32_bf16(ah[mt], bh[nt], acc[mt][nt], 0, 0, 0);
                acc[mt][nt] = __builtin_amdgcn_mfma_f32_16x16x32_bf16(ah[mt], bl[nt], acc[mt][nt], 0, 0, 0);
                acc[mt][nt] = __builtin_amdgcn_mfma_f32_16x16x32_bf16(al[mt], bh[nt], acc[mt][nt], 0, 0, 0);
            }
        __syncthreads();
    }
#pragma unroll
    for (int mt = 0; mt < 4; mt++) {
        int rbase = row0 + wr * 64 + mt * 16 + g * 4;
#pragma unroll
        for (int nt = 0; nt < 2; nt++) {
            int gc = col0 + wc * 32 + nt * 16 + l15;
            if (gc >= Nn) continue;
#pragma unroll
            for (int r = 0; r < 4; r++) {
                int gr = rbase + r;
                if (gr < M) {
                    float v = acc[mt][nt][r];
                    C[(size_t)gr * Nn + gc] = v;
                    Ch[(size_t)gr * Nn + gc] = (_Float16)v;
                }
            }
        }
    }
}

// ---------------- attention scores: si/sj [N,H] ----------------
__global__ __launch_bounds__(256) void score_kernel(const float* __restrict__ h,
                                                    const float* __restrict__ attI,
                                                    const float* __restrict__ attJ,
                                                    float* __restrict__ si,
                                                    float* __restrict__ sj, int F) {
    int n = blockIdx.x;
    int hd = threadIdx.x >> 6, lane = threadIdx.x & 63;
    const float* hrow = h + (size_t)n * (HEADS * F) + hd * F;
    float v1 = 0.f, v2 = 0.f;
    for (int f = lane; f < F; f += 64) {
        float xv = hrow[f];
        v1 = fmaf(xv, attI[hd * F + f], v1);
        v2 = fmaf(xv, attJ[hd * F + f], v2);
    }
#pragma unroll
    for (int off = 32; off; off >>= 1) {
        v1 += __shfl_xor(v1, off);
        v2 += __shfl_xor(v2, off);
    }
    if (lane == 0) {
        si[n * HEADS + hd] = v1;
        sj[n * HEADS + hd] = v2;
    }
}

// ---------------- aggregate (layers 1&2, F=64): wave = node ----------------
// lane l: head = l>>4, features 4l..4l+3 (fp16x4 = 8B gather -> 512B/edge/wave).
// pass 1: per-head online (m,d) on 16-lane groups; pass 2: 16-edge batches,
// indices shfl-broadcast, fp16 gather, fp32 accumulate.
template <bool ELU_OUT>
__global__ __launch_bounds__(256) void aggregate4_kernel(
        const _Float16* __restrict__ hH,   // [N][256] fp16
        const float* __restrict__ si, const float* __restrict__ sj,
        const int* __restrict__ rowStart, const int* __restrict__ eSrc,
        float* __restrict__ out, int N) {
    int wid = threadIdx.x >> 6;
    int n = blockIdx.x * 4 + wid;
    if (n >= N) return;
    int lane = threadIdx.x & 63;
    int hd = lane >> 4, g16 = lane & 15;
    int s0 = rowStart[n], s1 = rowStart[n + 1];
    float sin = si[n * HEADS + hd];

    // ---- pass 1: per-head online (m, d) over 16-lane group ----
    float m = -INFINITY, d = 0.f;
    for (int i = s0 + g16; i < s1; i += 16) {
        int s = eSrc[i];
        float e = sin + sj[s * HEADS + hd];
        e = fmaxf(e, SLOPE * e);
        float nm = fmaxf(m, e);
        d = d * __expf(m - nm) + __expf(e - nm);
        m = nm;
    }
#pragma unroll
    for (int off = 8; off; off >>= 1) {
        float om = __shfl_xor(m, off);
        float od = __shfl_xor(d, off);
        float nm = fmaxf(m, om);
        float w1 = (m == -INFINITY) ? 0.f : __expf(m - nm);
        float w2 = (om == -INFINITY) ? 0.f : __expf(om - nm);
        d = d * w1 + od * w2;
        m = nm;
    }
    float inv = (d > 0.f) ? 1.f / d : 0.f;

    // ---- pass 2: weighted accumulation, 16-edge batches ----
    float a0 = 0.f, a1 = 0.f, a2 = 0.f, a3 = 0.f;
    int i = s0;
    for (; i + 16 <= s1; i += 16) {
        int sv = eSrc[i + g16];
#pragma unroll
        for (int e = 0; e < 16; e++) {
            int s = __shfl(sv, e);
            float ee = sin + sj[s * HEADS + hd];
            ee = fmaxf(ee, SLOPE * ee);
            float w = __expf(ee - m);
            half4v hv = *(const half4v*)(hH + ((size_t)s << 8) + (lane << 2));
            a0 = fmaf(w, (float)hv[0], a0);
            a1 = fmaf(w, (float)hv[1], a1);
            a2 = fmaf(w, (float)hv[2], a2);
            a3 = fmaf(w, (float)hv[3], a3);
        }
    }
    if (i < s1) {
        int idx = i + g16;
        int sv = eSrc[(idx < s1) ? idx : (s1 - 1)];
        int rem = s1 - i;
        for (int e = 0; e < rem; e++) {
            int s = __shfl(sv, e);
            float ee = sin + sj[s * HEADS + hd];
            ee = fmaxf(ee, SLOPE * ee);
            float w = __expf(ee - m);
            half4v hv = *(const half4v*)(hH + ((size_t)s << 8) + (lane << 2));
            a0 = fmaf(w, (float)hv[0], a0);
            a1 = fmaf(w, (float)hv[1], a1);
            a2 = fmaf(w, (float)hv[2], a2);
            a3 = fmaf(w, (float)hv[3], a3);
        }
    }
    f32x4 o;
    o[0] = a0 * inv; o[1] = a1 * inv; o[2] = a2 * inv; o[3] = a3 * inv;
    if (ELU_OUT) {
#pragma unroll
        for (int e = 0; e < 4; e++) o[e] = (o[e] > 0.f) ? o[e] : expm1f(o[e]);
    }
    *(f32x4*)(out + ((size_t)n << 8) + (lane << 2)) = o;
}

// ---------------- final aggregate (layer 3, F=40): wave = (node, head) ----------------
// fp16 gather; mean over heads + log_softmax epilogue.
__global__ __launch_bounds__(256) void aggregate_final_kernel(
        const _Float16* __restrict__ hH,   // [N][160] fp16
        const float* __restrict__ si, const float* __restrict__ sj,
        const int* __restrict__ rowStart, const int* __restrict__ eSrc,
        float* __restrict__ out) {
    const int F = 40, D = 160;
    int n = blockIdx.x;
    int hd = threadIdx.x >> 6, lane = threadIdx.x & 63;
    int s0 = rowStart[n], s1 = rowStart[n + 1];
    float sin = si[n * HEADS + hd];

    float m = -INFINITY, d = 0.f;
    for (int i = s0 + lane; i < s1; i += 64) {
        int s = eSrc[i];
        float e = sin + sj[s * HEADS + hd];
        e = fmaxf(e, SLOPE * e);
        float nm = fmaxf(m, e);
        d = d * __expf(m - nm) + __expf(e - nm);
        m = nm;
    }
#pragma unroll
    for (int off = 32; off; off >>= 1) {
        float om = __shfl_xor(m, off);
        float od = __shfl_xor(d, off);
        float nm = fmaxf(m, om);
        float w1 = (m == -INFINITY) ? 0.f : __expf(m - nm);
        float w2 = (om == -INFINITY) ? 0.f : __expf(om - nm);
        d = d * w1 + od * w2;
        m = nm;
    }
    float inv = (d > 0.f) ? 1.f / d : 0.f;

    float acc = 0.f;
    for (int i = s0; i < s1; i++) {
        int s = eSrc[i];
        float e = sin + sj[s * HEADS + hd];
        e = fmaxf(e, SLOPE * e);
        float ex = __expf(e - m);
        if (lane < F) acc = fmaf(ex, (float)hH[(size_t)s * D + hd * F + lane], acc);
    }
    float val = acc * inv;

    __shared__ float tmp[HEADS][F];
    if (lane < F) tmp[hd][lane] = val;
    __syncthreads();
    if (hd == 0) {
        float x = (lane < F) ? 0.25f * (tmp[0][lane] + tmp[1][lane] + tmp[2][lane] + tmp[3][lane])
                             : -INFINITY;
        float mx = x;
#pragma unroll
        for (int off = 32; off; off >>= 1) mx = fmaxf(mx, __shfl_xor(mx, off));
        float ex = (lane < F) ? __expf(x - mx) : 0.f;
        float ssum = ex;
#pragma unroll
        for (int off = 32; off; off >>= 1) ssum += __shfl_xor(ssum, off);
        float ls = logf(ssum);
        if (lane < F) out[(size_t)n * F + lane] = (x - mx) - ls;
    }
}

// ---------------- launch ----------------
extern "C" void kernel_launch(void* const* d_in, const int* in_sizes, int n_in,
                              void* d_out, int out_size, void* d_ws, size_t ws_size,
                              hipStream_t stream) {
    const float* x   = (const float*)d_in[0];
    const int*   ei  = (const int*)d_in[1];
    const float* W1  = (const float*)d_in[2];
    const float* ai1 = (const float*)d_in[3];
    const float* aj1 = (const float*)d_in[4];
    const float* W2  = (const float*)d_in[5];
    const float* ai2 = (const float*)d_in[6];
    const float* aj2 = (const float*)d_in[7];
    const float* W3  = (const float*)d_in[8];
    const float* ai3 = (const float*)d_in[9];
    const float* aj3 = (const float*)d_in[10];

    const int IN_F = 256, HID = 64, NCLS = 40;
    const int N = in_sizes[0] / IN_F;   // 50000
    const int E = in_sizes[1] / 2;      // 800000
    const int D1 = HEADS * HID;         // 256
    const int D3 = HEADS * NCLS;        // 160

    const int* eSrcIn = ei;
    const int* eDstIn = ei + E;

    char* p = (char*)d_ws;
    auto carve = [&](size_t bytes) {
        char* r = p;
        p += (bytes + 255) & ~(size_t)255;
        return r;
    };
    float*     hA        = (float*)carve((size_t)N * D1 * 4);
    float*     hG        = (float*)carve((size_t)N * D1 * 4);
    _Float16*  hH        = (_Float16*)carve((size_t)N * D1 * 2);
    float*     si        = (float*)carve((size_t)N * HEADS * 4);
    float*     sj        = (float*)carve((size_t)N * HEADS * 4);
    int*       rowStart  = (int*)carve((size_t)(N + 1) * 4);
    int*       cursor    = (int*)carve((size_t)N * 4);
    int*       eSrc      = (int*)carve((size_t)E * 4);
    int*       blockSums = (int*)carve(1024);
    short*     W1hiT     = (short*)carve((size_t)IN_F * D1 * 2);
    short*     W1loT     = (short*)carve((size_t)IN_F * D1 * 2);
    short*     W2hiT     = (short*)carve((size_t)D1 * D1 * 2);
    short*     W2loT     = (short*)carve((size_t)D1 * D1 * 2);
    short*     W3hiT     = (short*)carve((size_t)D1 * D3 * 2);
    short*     W3loT     = (short*)carve((size_t)D1 * D3 * 2);

    int nbScan = cdiv(N, 256);

    // ---- W prep ----
    wsplit_kernel<<<cdiv(IN_F * D1, 256), 256, 0, stream>>>(W1, W1hiT, W1loT, IN_F, D1);
    wsplit_kernel<<<cdiv(D1 * D1, 256), 256, 0, stream>>>(W2, W2hiT, W2loT, D1, D1);
    wsplit_kernel<<<cdiv(D1 * D3, 256), 256, 0, stream>>>(W3, W3hiT, W3loT, D1, D3);

    // ---- CSR build ----
    hipMemsetAsync(cursor, 0, (size_t)N * 4, stream);
    hist_kernel<<<cdiv(E, 256), 256, 0, stream>>>(eDstIn, cursor, E);
    scan1_kernel<<<nbScan, 256, 0, stream>>>(cursor, rowStart, blockSums, N);
    scan2_kernel<<<1, 256, 0, stream>>>(blockSums, nbScan);
    scan3_kernel<<<cdiv(N + 1, 256), 256, 0, stream>>>(rowStart, blockSums, N, E);
    hipMemsetAsync(cursor, 0, (size_t)N * 4, stream);
    scatter_kernel<<<cdiv(E, 256), 256, 0, stream>>>(eSrcIn, eDstIn, rowStart, cursor, eSrc, E);

    dim3 g1(cdiv(D1, 64), cdiv(N, 128));
    dim3 g3(cdiv(D3, 64), cdiv(N, 128));

    // ---- layer 1 ----
    gemm_mfma_kernel<<<g1, 256, 0, stream>>>(x, W1hiT, W1loT, hG, hH, N, IN_F, D1);
    score_kernel<<<N, 256, 0, stream>>>(hG, ai1, aj1, si, sj, HID);
    aggregate4_kernel<true><<<cdiv(N, 4), 256, 0, stream>>>(hH, si, sj, rowStart, eSrc, hA, N);

    // ---- layer 2 ----
    gemm_mfma_kernel<<<g1, 256, 0, stream>>>(hA, W2hiT, W2loT, hG, hH, N, D1, D1);
    score_kernel<<<N, 256, 0, stream>>>(hG, ai2, aj2, si, sj, HID);
    aggregate4_kernel<true><<<cdiv(N, 4), 256, 0, stream>>>(hH, si, sj, rowStart, eSrc, hA, N);

    // ---- layer 3 ----
    gemm_mfma_kernel<<<g3, 256, 0, stream>>>(hA, W3hiT, W3loT, hG, hH, N, D1, D3);
    score_kernel<<<N, 256, 0, stream>>>(hG, ai3, aj3, si, sj, NCLS);
    aggregate_final_kernel<<<N, 256, 0, stream>>>(hH, si, sj, rowStart, eSrc, (float*)d_out);
}

// Round 5
// 682.650 us; speedup vs baseline: 1.6332x; 1.1588x over previous
//
#include <hip/hip_runtime.h>
#include <math.h>

// GAT 3-layer forward on MI355X.
//   CSR build (histogram -> scan -> scatter by dst)
//   W-prep: split each W into (hi,lo) bf16 and transpose to [n][k]
//   L1..L3: gemm_mfma (3x bf16-split, writes fp32 + fp16 copies) -> score -> aggregate
// Aggregates: wave = node (all 4 heads), fp16 batched gather with shfl-broadcast
// edge indices (16 in flight). No atomics anywhere in the hot path.

#define HEADS 4
#define SLOPE 0.2f

typedef __attribute__((ext_vector_type(4))) float  f32x4;
typedef __attribute__((ext_vector_type(4))) short  short4v;
typedef __attribute__((ext_vector_type(8))) short  short8v;
typedef __attribute__((ext_vector_type(4))) _Float16 half4v;

static inline int cdiv(int a, int b) { return (a + b - 1) / b; }

// fp32 -> bf16 hi (truncate) + bf16 lo (truncate of exact remainder).
__device__ inline void split_bf16(float x, short& hi, short& lo) {
    unsigned b = __float_as_uint(x);
    hi = (short)(b >> 16);
    float hif = __uint_as_float(b & 0xffff0000u);
    float rem = x - hif;  // exact
    lo = (short)(__float_as_uint(rem) >> 16);
}

// ---------------- CSR build ----------------
__global__ void hist_kernel(const int* __restrict__ dst, int* __restrict__ cnt, int E) {
    int i = blockIdx.x * blockDim.x + threadIdx.x;
    if (i < E) atomicAdd(&cnt[dst[i]], 1);
}

__global__ void scan1_kernel(const int* __restrict__ cnt, int* __restrict__ rowStart,
                             int* __restrict__ blockSums, int N) {
    __shared__ int s[256];
    int t = threadIdx.x;
    int i = blockIdx.x * 256 + t;
    int v = (i < N) ? cnt[i] : 0;
    s[t] = v;
    for (int off = 1; off < 256; off <<= 1) {
        __syncthreads();
        int add = (t >= off) ? s[t - off] : 0;
        __syncthreads();
        s[t] += add;
    }
    __syncthreads();
    if (i < N) rowStart[i] = s[t] - v;
    if (t == 255) blockSums[blockIdx.x] = s[255];
}

__global__ void scan2_kernel(int* blockSums, int nb) {
    __shared__ int s[256];
    int t = threadIdx.x;
    int v = (t < nb) ? blockSums[t] : 0;
    s[t] = v;
    for (int off = 1; off < 256; off <<= 1) {
        __syncthreads();
        int add = (t >= off) ? s[t - off] : 0;
        __syncthreads();
        s[t] += add;
    }
    if (t < nb) blockSums[t] = s[t] - v;
}

__global__ void scan3_kernel(int* rowStart, const int* __restrict__ blockSums, int N, int E) {
    int i = blockIdx.x * 256 + threadIdx.x;
    if (i < N) rowStart[i] += blockSums[i >> 8];
    else if (i == N) rowStart[N] = E;
}

__global__ void scatter_kernel(const int* __restrict__ src, const int* __restrict__ dst,
                               const int* __restrict__ rowStart, int* __restrict__ cursor,
                               int* __restrict__ eSrc, int E) {
    int i = blockIdx.x * blockDim.x + threadIdx.x;
    if (i < E) {
        int d = dst[i];
        int pos = rowStart[d] + atomicAdd(&cursor[d], 1);
        eSrc[pos] = src[i];
    }
}

// ---------------- W prep: split + transpose ----------------
__global__ void wsplit_kernel(const float* __restrict__ W, short* __restrict__ hiT,
                              short* __restrict__ loT, int K, int Nn) {
    int id = blockIdx.x * 256 + threadIdx.x;
    if (id >= K * Nn) return;
    int k = id / Nn, n = id - k * Nn;
    short h, l;
    split_bf16(W[id], h, l);
    hiT[n * K + k] = h;
    loT[n * K + k] = l;
}

// ---------------- MFMA GEMM: C[M,Nn] = A[M,K] @ W[K,Nn] ----------------
// 3x bf16-split; writes fp32 C and fp16 copy Ch.
__global__ __launch_bounds__(256) void gemm_mfma_kernel(
        const float* __restrict__ A, const short* __restrict__ BhiT,
        const short* __restrict__ BloT, float* __restrict__ C,
        _Float16* __restrict__ Ch, int M, int K, int Nn) {
    __shared__ short Ahi[128 * 40];
    __shared__ short Alo[128 * 40];
    __shared__ short Bhi[64 * 40];
    __shared__ short Blo[64 * 40];
    int t = threadIdx.x;
    int lane = t & 63, wid = t >> 6;
    int wr = wid >> 1, wc = wid & 1;
    int l15 = lane & 15, g = lane >> 4;
    int row0 = blockIdx.y * 128, col0 = blockIdx.x * 64;

    f32x4 acc[4][2] = {};

    for (int k0 = 0; k0 < K; k0 += 32) {
#pragma unroll
        for (int i = 0; i < 4; i++) {
            int q = t + i * 256;
            int r = q >> 3, qc = q & 7;
            int gr = row0 + r;
            f32x4 v = {};
            if (gr < M) v = *(const f32x4*)(A + (size_t)gr * K + k0 + qc * 4);
            short4v h4, l4;
#pragma unroll
            for (int e = 0; e < 4; e++) {
                short hh, ll;
                split_bf16(v[e], hh, ll);
                h4[e] = hh;
                l4[e] = ll;
            }
            *(short4v*)(Ahi + r * 40 + qc * 4) = h4;
            *(short4v*)(Alo + r * 40 + qc * 4) = l4;
        }
        {
            int n = t >> 2, kq = t & 3;
            int gc = col0 + n;
            short8v h8 = {}, l8 = {};
            if (gc < Nn) {
                h8 = *(const short8v*)(BhiT + (size_t)gc * K + k0 + kq * 8);
                l8 = *(const short8v*)(BloT + (size_t)gc * K + k0 + kq * 8);
            }
            *(short8v*)(Bhi + n * 40 + kq * 8) = h8;
            *(short8v*)(Blo + n * 40 + kq * 8) = l8;
        }
        __syncthreads();
        short8v ah[4], al[4], bh[2], bl[2];
#pragma unroll
        for (int mt = 0; mt < 4; mt++) {
            int r = wr * 64 + mt * 16 + l15;
            ah[mt] = *(const short8v*)(Ahi + r * 40 + g * 8);
            al[mt] = *(const short8v*)(Alo + r * 40 + g * 8);
        }
#pragma unroll
        for (int nt = 0; nt < 2; nt++) {
            int n = wc * 32 + nt * 16 + l15;
            bh[nt] = *(const short8v*)(Bhi + n * 40 + g * 8);
            bl[nt] = *(const short8v*)(Blo + n * 40 + g * 8);
        }
#pragma unroll
        for (int mt = 0; mt < 4; mt++)
#pragma unroll
            for (int nt = 0; nt < 2; nt++) {
                acc[mt][nt] = __builtin_amdgcn_mfma_f32_16x16x32_bf16(ah[mt], bh[nt], acc[mt][nt], 0, 0, 0);
                acc[mt][nt] = __builtin_amdgcn_mfma_f32_16x16x32_bf16(ah[mt], bl[nt], acc[mt][nt], 0, 0, 0);
                acc[mt][nt] = __builtin_amdgcn_mfma_f32_16x16x32_bf16(al[mt], bh[nt], acc[mt][nt], 0, 0, 0);
            }
        __syncthreads();
    }
#pragma unroll
    for (int mt = 0; mt < 4; mt++) {
        int rbase = row0 + wr * 64 + mt * 16 + g * 4;
#pragma unroll
        for (int nt = 0; nt < 2; nt++) {
            int gc = col0 + wc * 32 + nt * 16 + l15;
            if (gc >= Nn) continue;
#pragma unroll
            for (int r = 0; r < 4; r++) {
                int gr = rbase + r;
                if (gr < M) {
                    float v = acc[mt][nt][r];
                    C[(size_t)gr * Nn + gc] = v;
                    Ch[(size_t)gr * Nn + gc] = (_Float16)v;
                }
            }
        }
    }
}

// ---------------- attention scores: si/sj [N,H] ----------------
__global__ __launch_bounds__(256) void score_kernel(const float* __restrict__ h,
                                                    const float* __restrict__ attI,
                                                    const float* __restrict__ attJ,
                                                    float* __restrict__ si,
                                                    float* __restrict__ sj, int F) {
    int n = blockIdx.x;
    int hd = threadIdx.x >> 6, lane = threadIdx.x & 63;
    const float* hrow = h + (size_t)n * (HEADS * F) + hd * F;
    float v1 = 0.f, v2 = 0.f;
    for (int f = lane; f < F; f += 64) {
        float xv = hrow[f];
        v1 = fmaf(xv, attI[hd * F + f], v1);
        v2 = fmaf(xv, attJ[hd * F + f], v2);
    }
#pragma unroll
    for (int off = 32; off; off >>= 1) {
        v1 += __shfl_xor(v1, off);
        v2 += __shfl_xor(v2, off);
    }
    if (lane == 0) {
        si[n * HEADS + hd] = v1;
        sj[n * HEADS + hd] = v2;
    }
}

// ---------------- aggregate (layers 1&2, F=64): wave = node ----------------
// lane l: head = l>>4, features 4l..4l+3 (fp16x4 = 8B gather -> 512B/edge/wave).
template <bool ELU_OUT>
__global__ __launch_bounds__(256) void aggregate4_kernel(
        const _Float16* __restrict__ hH,   // [N][256] fp16
        const float* __restrict__ si, const float* __restrict__ sj,
        const int* __restrict__ rowStart, const int* __restrict__ eSrc,
        float* __restrict__ out, int N) {
    int wid = threadIdx.x >> 6;
    int n = blockIdx.x * 4 + wid;
    if (n >= N) return;
    int lane = threadIdx.x & 63;
    int hd = lane >> 4, g16 = lane & 15;
    int s0 = rowStart[n], s1 = rowStart[n + 1];
    float sin = si[n * HEADS + hd];

    // ---- pass 1: per-head online (m, d) over 16-lane group ----
    float m = -INFINITY, d = 0.f;
    for (int i = s0 + g16; i < s1; i += 16) {
        int s = eSrc[i];
        float e = sin + sj[s * HEADS + hd];
        e = fmaxf(e, SLOPE * e);
        float nm = fmaxf(m, e);
        d = d * __expf(m - nm) + __expf(e - nm);
        m = nm;
    }
#pragma unroll
    for (int off = 8; off; off >>= 1) {
        float om = __shfl_xor(m, off);
        float od = __shfl_xor(d, off);
        float nm = fmaxf(m, om);
        float w1 = (m == -INFINITY) ? 0.f : __expf(m - nm);
        float w2 = (om == -INFINITY) ? 0.f : __expf(om - nm);
        d = d * w1 + od * w2;
        m = nm;
    }
    float inv = (d > 0.f) ? 1.f / d : 0.f;

    // ---- pass 2: weighted accumulation, 16-edge batches ----
    float a0 = 0.f, a1 = 0.f, a2 = 0.f, a3 = 0.f;
    int i = s0;
    for (; i + 16 <= s1; i += 16) {
        int sv = eSrc[i + g16];
#pragma unroll
        for (int e = 0; e < 16; e++) {
            int s = __shfl(sv, e);
            float ee = sin + sj[s * HEADS + hd];
            ee = fmaxf(ee, SLOPE * ee);
            float w = __expf(ee - m);
            half4v hv = *(const half4v*)(hH + ((size_t)s << 8) + (lane << 2));
            a0 = fmaf(w, (float)hv[0], a0);
            a1 = fmaf(w, (float)hv[1], a1);
            a2 = fmaf(w, (float)hv[2], a2);
            a3 = fmaf(w, (float)hv[3], a3);
        }
    }
    if (i < s1) {
        int idx = i + g16;
        int sv = eSrc[(idx < s1) ? idx : (s1 - 1)];
        int rem = s1 - i;
        for (int e = 0; e < rem; e++) {
            int s = __shfl(sv, e);
            float ee = sin + sj[s * HEADS + hd];
            ee = fmaxf(ee, SLOPE * ee);
            float w = __expf(ee - m);
            half4v hv = *(const half4v*)(hH + ((size_t)s << 8) + (lane << 2));
            a0 = fmaf(w, (float)hv[0], a0);
            a1 = fmaf(w, (float)hv[1], a1);
            a2 = fmaf(w, (float)hv[2], a2);
            a3 = fmaf(w, (float)hv[3], a3);
        }
    }
    f32x4 o;
    o[0] = a0 * inv; o[1] = a1 * inv; o[2] = a2 * inv; o[3] = a3 * inv;
    if (ELU_OUT) {
#pragma unroll
        for (int e = 0; e < 4; e++) o[e] = (o[e] > 0.f) ? o[e] : expm1f(o[e]);
    }
    *(f32x4*)(out + ((size_t)n << 8) + (lane << 2)) = o;
}

// ---------------- final aggregate (layer 3): wave = node, all heads ----------------
// hH row = 160 fp16 = 320B. Lanes 0..39 gather half4 (feature 4l, head l/10).
// pass 1 identical to aggregate4 (16-lane groups per head); pass 2 redistributes
// (m, inv, si) via shfl from lane hd*16. Epilogue: mean over heads + log_softmax
// wave-locally via a 160-float LDS stripe per wave.
__global__ __launch_bounds__(256) void aggregate_final_kernel(
        const _Float16* __restrict__ hH,   // [N][160] fp16
        const float* __restrict__ si, const float* __restrict__ sj,
        const int* __restrict__ rowStart, const int* __restrict__ eSrc,
        float* __restrict__ out, int N) {
    const int NCLS = 40, D = 160;
    __shared__ float tmp[4][D];
    int wid = threadIdx.x >> 6;
    int n = blockIdx.x * 4 + wid;
    if (n >= N) return;
    int lane = threadIdx.x & 63;
    int hd1 = lane >> 4, g16 = lane & 15;
    int s0 = rowStart[n], s1 = rowStart[n + 1];
    float sin1 = si[n * HEADS + hd1];

    // ---- pass 1: per-head online (m, d) ----
    float m = -INFINITY, d = 0.f;
    for (int i = s0 + g16; i < s1; i += 16) {
        int s = eSrc[i];
        float e = sin1 + sj[s * HEADS + hd1];
        e = fmaxf(e, SLOPE * e);
        float nm = fmaxf(m, e);
        d = d * __expf(m - nm) + __expf(e - nm);
        m = nm;
    }
#pragma unroll
    for (int off = 8; off; off >>= 1) {
        float om = __shfl_xor(m, off);
        float od = __shfl_xor(d, off);
        float nm = fmaxf(m, om);
        float w1 = (m == -INFINITY) ? 0.f : __expf(m - nm);
        float w2 = (om == -INFINITY) ? 0.f : __expf(om - nm);
        d = d * w1 + od * w2;
        m = nm;
    }
    float inv = (d > 0.f) ? 1.f / d : 0.f;

    // ---- redistribute per-head stats for pass-2 lane layout ----
    int hd2 = (lane < NCLS) ? (lane / 10) : 3;
    float m2   = __shfl(m,   hd2 << 4);
    float inv2 = __shfl(inv, hd2 << 4);
    float sin2 = __shfl(sin1, hd2 << 4);

    // ---- pass 2: 16-edge batches, 40-lane half4 gathers ----
    float a0 = 0.f, a1 = 0.f, a2 = 0.f, a3 = 0.f;
    int i = s0;
    for (; i + 16 <= s1; i += 16) {
        int sv = eSrc[i + g16];
#pragma unroll
        for (int e = 0; e < 16; e++) {
            int s = __shfl(sv, e);
            float ee = sin2 + sj[s * HEADS + hd2];
            ee = fmaxf(ee, SLOPE * ee);
            float w = __expf(ee - m2);
            if (lane < NCLS) {
                half4v hv = *(const half4v*)(hH + (size_t)s * D + (lane << 2));
                a0 = fmaf(w, (float)hv[0], a0);
                a1 = fmaf(w, (float)hv[1], a1);
                a2 = fmaf(w, (float)hv[2], a2);
                a3 = fmaf(w, (float)hv[3], a3);
            }
        }
    }
    if (i < s1) {
        int idx = i + g16;
        int sv = eSrc[(idx < s1) ? idx : (s1 - 1)];
        int rem = s1 - i;
        for (int e = 0; e < rem; e++) {
            int s = __shfl(sv, e);
            float ee = sin2 + sj[s * HEADS + hd2];
            ee = fmaxf(ee, SLOPE * ee);
            float w = __expf(ee - m2);
            if (lane < NCLS) {
                half4v hv = *(const half4v*)(hH + (size_t)s * D + (lane << 2));
                a0 = fmaf(w, (float)hv[0], a0);
                a1 = fmaf(w, (float)hv[1], a1);
                a2 = fmaf(w, (float)hv[2], a2);
                a3 = fmaf(w, (float)hv[3], a3);
            }
        }
    }
    // ---- epilogue: mean over heads + log_softmax (wave-local) ----
    if (lane < NCLS) {
        tmp[wid][(lane << 2) + 0] = a0 * inv2;
        tmp[wid][(lane << 2) + 1] = a1 * inv2;
        tmp[wid][(lane << 2) + 2] = a2 * inv2;
        tmp[wid][(lane << 2) + 3] = a3 * inv2;
    }
    __builtin_amdgcn_wave_barrier();  // same wave: LDS writes then reads, in-order
    float x = -INFINITY;
    if (lane < NCLS)
        x = 0.25f * (tmp[wid][lane] + tmp[wid][NCLS + lane] +
                     tmp[wid][2 * NCLS + lane] + tmp[wid][3 * NCLS + lane]);
    float mx = x;
#pragma unroll
    for (int off = 32; off; off >>= 1) mx = fmaxf(mx, __shfl_xor(mx, off));
    float ex = (lane < NCLS) ? __expf(x - mx) : 0.f;
    float ssum = ex;
#pragma unroll
    for (int off = 32; off; off >>= 1) ssum += __shfl_xor(ssum, off);
    float ls = logf(ssum);
    if (lane < NCLS) out[(size_t)n * NCLS + lane] = (x - mx) - ls;
}

// ---------------- launch ----------------
extern "C" void kernel_launch(void* const* d_in, const int* in_sizes, int n_in,
                              void* d_out, int out_size, void* d_ws, size_t ws_size,
                              hipStream_t stream) {
    const float* x   = (const float*)d_in[0];
    const int*   ei  = (const int*)d_in[1];
    const float* W1  = (const float*)d_in[2];
    const float* ai1 = (const float*)d_in[3];
    const float* aj1 = (const float*)d_in[4];
    const float* W2  = (const float*)d_in[5];
    const float* ai2 = (const float*)d_in[6];
    const float* aj2 = (const float*)d_in[7];
    const float* W3  = (const float*)d_in[8];
    const float* ai3 = (const float*)d_in[9];
    const float* aj3 = (const float*)d_in[10];

    const int IN_F = 256, HID = 64, NCLS = 40;
    const int N = in_sizes[0] / IN_F;   // 50000
    const int E = in_sizes[1] / 2;      // 800000
    const int D1 = HEADS * HID;         // 256
    const int D3 = HEADS * NCLS;        // 160

    const int* eSrcIn = ei;
    const int* eDstIn = ei + E;

    char* p = (char*)d_ws;
    auto carve = [&](size_t bytes) {
        char* r = p;
        p += (bytes + 255) & ~(size_t)255;
        return r;
    };
    float*     hA        = (float*)carve((size_t)N * D1 * 4);
    float*     hG        = (float*)carve((size_t)N * D1 * 4);
    _Float16*  hH        = (_Float16*)carve((size_t)N * D1 * 2);
    float*     si        = (float*)carve((size_t)N * HEADS * 4);
    float*     sj        = (float*)carve((size_t)N * HEADS * 4);
    int*       rowStart  = (int*)carve((size_t)(N + 1) * 4);
    int*       cursor    = (int*)carve((size_t)N * 4);
    int*       eSrc      = (int*)carve((size_t)E * 4);
    int*       blockSums = (int*)carve(1024);
    short*     W1hiT     = (short*)carve((size_t)IN_F * D1 * 2);
    short*     W1loT     = (short*)carve((size_t)IN_F * D1 * 2);
    short*     W2hiT     = (short*)carve((size_t)D1 * D1 * 2);
    short*     W2loT     = (short*)carve((size_t)D1 * D1 * 2);
    short*     W3hiT     = (short*)carve((size_t)D1 * D3 * 2);
    short*     W3loT     = (short*)carve((size_t)D1 * D3 * 2);

    int nbScan = cdiv(N, 256);

    // ---- W prep ----
    wsplit_kernel<<<cdiv(IN_F * D1, 256), 256, 0, stream>>>(W1, W1hiT, W1loT, IN_F, D1);
    wsplit_kernel<<<cdiv(D1 * D1, 256), 256, 0, stream>>>(W2, W2hiT, W2loT, D1, D1);
    wsplit_kernel<<<cdiv(D1 * D3, 256), 256, 0, stream>>>(W3, W3hiT, W3loT, D1, D3);

    // ---- CSR build ----
    hipMemsetAsync(cursor, 0, (size_t)N * 4, stream);
    hist_kernel<<<cdiv(E, 256), 256, 0, stream>>>(eDstIn, cursor, E);
    scan1_kernel<<<nbScan, 256, 0, stream>>>(cursor, rowStart, blockSums, N);
    scan2_kernel<<<1, 256, 0, stream>>>(blockSums, nbScan);
    scan3_kernel<<<cdiv(N + 1, 256), 256, 0, stream>>>(rowStart, blockSums, N, E);
    hipMemsetAsync(cursor, 0, (size_t)N * 4, stream);
    scatter_kernel<<<cdiv(E, 256), 256, 0, stream>>>(eSrcIn, eDstIn, rowStart, cursor, eSrc, E);

    dim3 g1(cdiv(D1, 64), cdiv(N, 128));
    dim3 g3(cdiv(D3, 64), cdiv(N, 128));

    // ---- layer 1 ----
    gemm_mfma_kernel<<<g1, 256, 0, stream>>>(x, W1hiT, W1loT, hG, hH, N, IN_F, D1);
    score_kernel<<<N, 256, 0, stream>>>(hG, ai1, aj1, si, sj, HID);
    aggregate4_kernel<true><<<cdiv(N, 4), 256, 0, stream>>>(hH, si, sj, rowStart, eSrc, hA, N);

    // ---- layer 2 ----
    gemm_mfma_kernel<<<g1, 256, 0, stream>>>(hA, W2hiT, W2loT, hG, hH, N, D1, D1);
    score_kernel<<<N, 256, 0, stream>>>(hG, ai2, aj2, si, sj, HID);
    aggregate4_kernel<true><<<cdiv(N, 4), 256, 0, stream>>>(hH, si, sj, rowStart, eSrc, hA, N);

    // ---- layer 3 ----
    gemm_mfma_kernel<<<g3, 256, 0, stream>>>(hA, W3hiT, W3loT, hG, hH, N, D1, D3);
    score_kernel<<<N, 256, 0, stream>>>(hG, ai3, aj3, si, sj, NCLS);
    aggregate_final_kernel<<<cdiv(N, 4), 256, 0, stream>>>(hH, si, sj, rowStart, eSrc, (float*)d_out, N);
}

// Round 8
// 593.495 us; speedup vs baseline: 1.8786x; 1.1502x over previous
//
#include <hip/hip_runtime.h>
#include <math.h>

// GAT 3-layer forward on MI355X.
//   CSR build (histogram -> scan -> scatter by dst)
//   W-prep: split each W into (hi,lo) bf16 and transpose to [n][k]
//   L1..L3: gemm_mfma (3x bf16-split, writes fp16 h only) -> score16 -> aggregate
// Aggregates: wave = node (all 4 heads), fp16 batched gather; per-batch edge
// weights computed once per (edge,head) lane and shfl-broadcast. No atomics.

#define HEADS 4
#define SLOPE 0.2f

typedef __attribute__((ext_vector_type(4))) float  f32x4;
typedef __attribute__((ext_vector_type(4))) short  short4v;
typedef __attribute__((ext_vector_type(8))) short  short8v;
typedef __attribute__((ext_vector_type(4))) _Float16 half4v;

static inline int cdiv(int a, int b) { return (a + b - 1) / b; }

// fp32 -> bf16 hi (truncate) + bf16 lo (truncate of exact remainder).
__device__ inline void split_bf16(float x, short& hi, short& lo) {
    unsigned b = __float_as_uint(x);
    hi = (short)(b >> 16);
    float hif = __uint_as_float(b & 0xffff0000u);
    float rem = x - hif;  // exact
    lo = (short)(__float_as_uint(rem) >> 16);
}

// ---------------- CSR build ----------------
__global__ void hist_kernel(const int* __restrict__ dst, int* __restrict__ cnt, int E) {
    int i = blockIdx.x * blockDim.x + threadIdx.x;
    if (i < E) atomicAdd(&cnt[dst[i]], 1);
}

__global__ void scan1_kernel(const int* __restrict__ cnt, int* __restrict__ rowStart,
                             int* __restrict__ blockSums, int N) {
    __shared__ int s[256];
    int t = threadIdx.x;
    int i = blockIdx.x * 256 + t;
    int v = (i < N) ? cnt[i] : 0;
    s[t] = v;
    for (int off = 1; off < 256; off <<= 1) {
        __syncthreads();
        int add = (t >= off) ? s[t - off] : 0;
        __syncthreads();
        s[t] += add;
    }
    __syncthreads();
    if (i < N) rowStart[i] = s[t] - v;
    if (t == 255) blockSums[blockIdx.x] = s[255];
}

__global__ void scan2_kernel(int* blockSums, int nb) {
    __shared__ int s[256];
    int t = threadIdx.x;
    int v = (t < nb) ? blockSums[t] : 0;
    s[t] = v;
    for (int off = 1; off < 256; off <<= 1) {
        __syncthreads();
        int add = (t >= off) ? s[t - off] : 0;
        __syncthreads();
        s[t] += add;
    }
    if (t < nb) blockSums[t] = s[t] - v;
}

__global__ void scan3_kernel(int* rowStart, const int* __restrict__ blockSums, int N, int E) {
    int i = blockIdx.x * 256 + threadIdx.x;
    if (i < N) rowStart[i] += blockSums[i >> 8];
    else if (i == N) rowStart[N] = E;
}

__global__ void scatter_kernel(const int* __restrict__ src, const int* __restrict__ dst,
                               const int* __restrict__ rowStart, int* __restrict__ cursor,
                               int* __restrict__ eSrc, int E) {
    int i = blockIdx.x * blockDim.x + threadIdx.x;
    if (i < E) {
        int d = dst[i];
        int pos = rowStart[d] + atomicAdd(&cursor[d], 1);
        eSrc[pos] = src[i];
    }
}

// ---------------- W prep: split + transpose ----------------
__global__ void wsplit_kernel(const float* __restrict__ W, short* __restrict__ hiT,
                              short* __restrict__ loT, int K, int Nn) {
    int id = blockIdx.x * 256 + threadIdx.x;
    if (id >= K * Nn) return;
    int k = id / Nn, n = id - k * Nn;
    short h, l;
    split_bf16(W[id], h, l);
    hiT[n * K + k] = h;
    loT[n * K + k] = l;
}

// ---------------- MFMA GEMM: Ch[M,Nn] = fp16(A[M,K] @ W[K,Nn]) ----------------
// 3x bf16-split (hi*hi + hi*lo + lo*hi), fp32 accumulate, fp16 output only.
__global__ __launch_bounds__(256) void gemm_mfma_kernel(
        const float* __restrict__ A, const short* __restrict__ BhiT,
        const short* __restrict__ BloT, _Float16* __restrict__ Ch,
        int M, int K, int Nn) {
    __shared__ short Ahi[128 * 40];
    __shared__ short Alo[128 * 40];
    __shared__ short Bhi[64 * 40];
    __shared__ short Blo[64 * 40];
    int t = threadIdx.x;
    int lane = t & 63, wid = t >> 6;
    int wr = wid >> 1, wc = wid & 1;
    int l15 = lane & 15, g = lane >> 4;
    int row0 = blockIdx.y * 128, col0 = blockIdx.x * 64;

    f32x4 acc[4][2] = {};

    for (int k0 = 0; k0 < K; k0 += 32) {
#pragma unroll
        for (int i = 0; i < 4; i++) {
            int q = t + i * 256;
            int r = q >> 3, qc = q & 7;
            int gr = row0 + r;
            f32x4 v = {};
            if (gr < M) v = *(const f32x4*)(A + (size_t)gr * K + k0 + qc * 4);
            short4v h4, l4;
#pragma unroll
            for (int e = 0; e < 4; e++) {
                short hh, ll;
                split_bf16(v[e], hh, ll);
                h4[e] = hh;
                l4[e] = ll;
            }
            *(short4v*)(Ahi + r * 40 + qc * 4) = h4;
            *(short4v*)(Alo + r * 40 + qc * 4) = l4;
        }
        {
            int n = t >> 2, kq = t & 3;
            int gc = col0 + n;
            short8v h8 = {}, l8 = {};
            if (gc < Nn) {
                h8 = *(const short8v*)(BhiT + (size_t)gc * K + k0 + kq * 8);
                l8 = *(const short8v*)(BloT + (size_t)gc * K + k0 + kq * 8);
            }
            *(short8v*)(Bhi + n * 40 + kq * 8) = h8;
            *(short8v*)(Blo + n * 40 + kq * 8) = l8;
        }
        __syncthreads();
        short8v ah[4], al[4], bh[2], bl[2];
#pragma unroll
        for (int mt = 0; mt < 4; mt++) {
            int r = wr * 64 + mt * 16 + l15;
            ah[mt] = *(const short8v*)(Ahi + r * 40 + g * 8);
            al[mt] = *(const short8v*)(Alo + r * 40 + g * 8);
        }
#pragma unroll
        for (int nt = 0; nt < 2; nt++) {
            int n = wc * 32 + nt * 16 + l15;
            bh[nt] = *(const short8v*)(Bhi + n * 40 + g * 8);
            bl[nt] = *(const short8v*)(Blo + n * 40 + g * 8);
        }
#pragma unroll
        for (int mt = 0; mt < 4; mt++)
#pragma unroll
            for (int nt = 0; nt < 2; nt++) {
                acc[mt][nt] = __builtin_amdgcn_mfma_f32_16x16x32_bf16(ah[mt], bh[nt], acc[mt][nt], 0, 0, 0);
                acc[mt][nt] = __builtin_amdgcn_mfma_f32_16x16x32_bf16(ah[mt], bl[nt], acc[mt][nt], 0, 0, 0);
                acc[mt][nt] = __builtin_amdgcn_mfma_f32_16x16x32_bf16(al[mt], bh[nt], acc[mt][nt], 0, 0, 0);
            }
        __syncthreads();
    }
#pragma unroll
    for (int mt = 0; mt < 4; mt++) {
        int rbase = row0 + wr * 64 + mt * 16 + g * 4;
#pragma unroll
        for (int nt = 0; nt < 2; nt++) {
            int gc = col0 + wc * 32 + nt * 16 + l15;
            if (gc >= Nn) continue;
#pragma unroll
            for (int r = 0; r < 4; r++) {
                int gr = rbase + r;
                if (gr < M) Ch[(size_t)gr * Nn + gc] = (_Float16)acc[mt][nt][r];
            }
        }
    }
}

// ---------------- attention scores from fp16 h: si/sj [N,H] ----------------
// wave = node; lane (hd, g16): half4 at feature 4*g16 of head hd; 16-lane reduce.
template <int F>
__global__ __launch_bounds__(256) void score16_kernel(
        const _Float16* __restrict__ hH, const float* __restrict__ attI,
        const float* __restrict__ attJ, float* __restrict__ si,
        float* __restrict__ sj, int N) {
    const int D = HEADS * F;
    int wid = threadIdx.x >> 6;
    int n = blockIdx.x * 4 + wid;
    if (n >= N) return;
    int lane = threadIdx.x & 63;
    int hd = lane >> 4, g16 = lane & 15;
    float v1 = 0.f, v2 = 0.f;
    if (g16 * 4 < F) {
        half4v hv = *(const half4v*)(hH + (size_t)n * D + hd * F + g16 * 4);
        f32x4 ai = *(const f32x4*)(attI + hd * F + g16 * 4);
        f32x4 aj = *(const f32x4*)(attJ + hd * F + g16 * 4);
#pragma unroll
        for (int e = 0; e < 4; e++) {
            float xv = (float)hv[e];
            v1 = fmaf(xv, ai[e], v1);
            v2 = fmaf(xv, aj[e], v2);
        }
    }
#pragma unroll
    for (int off = 8; off; off >>= 1) {
        v1 += __shfl_xor(v1, off);
        v2 += __shfl_xor(v2, off);
    }
    if (g16 == 0) {
        si[n * HEADS + hd] = v1;
        sj[n * HEADS + hd] = v2;
    }
}

// ---------------- aggregate (layers 1&2, F=64): wave = node ----------------
// pass 1: per-head online (m,d) on 16-lane groups.
// pass 2: per 16-edge batch, lane (hd,g16) computes weight(edge g16, head hd)
// once; inner loop shfl-broadcasts src index + weight, gathers fp16x4.
template <bool ELU_OUT>
__global__ __launch_bounds__(256) void aggregate4_kernel(
        const _Float16* __restrict__ hH,   // [N][256] fp16
        const float* __restrict__ si, const float* __restrict__ sj,
        const int* __restrict__ rowStart, const int* __restrict__ eSrc,
        float* __restrict__ out, int N) {
    int wid = threadIdx.x >> 6;
    int n = blockIdx.x * 4 + wid;
    if (n >= N) return;
    int lane = threadIdx.x & 63;
    int hd = lane >> 4, g16 = lane & 15;
    int s0 = rowStart[n], s1 = rowStart[n + 1];
    float sin = si[n * HEADS + hd];

    // ---- pass 1: per-head online (m, d) over 16-lane group ----
    float m = -INFINITY, d = 0.f;
    for (int i = s0 + g16; i < s1; i += 16) {
        int s = eSrc[i];
        float e = sin + sj[s * HEADS + hd];
        e = fmaxf(e, SLOPE * e);
        float nm = fmaxf(m, e);
        d = d * __expf(m - nm) + __expf(e - nm);
        m = nm;
    }
#pragma unroll
    for (int off = 8; off; off >>= 1) {
        float om = __shfl_xor(m, off);
        float od = __shfl_xor(d, off);
        float nm = fmaxf(m, om);
        float w1 = (m == -INFINITY) ? 0.f : __expf(m - nm);
        float w2 = (om == -INFINITY) ? 0.f : __expf(om - nm);
        d = d * w1 + od * w2;
        m = nm;
    }
    float inv = (d > 0.f) ? 1.f / d : 0.f;

    // ---- pass 2 ----
    float a0 = 0.f, a1 = 0.f, a2 = 0.f, a3 = 0.f;
    int i = s0;
    for (; i + 16 <= s1; i += 16) {
        int sv = eSrc[i + g16];
        float ee = sin + sj[sv * HEADS + hd];
        ee = fmaxf(ee, SLOPE * ee);
        float wv = __expf(ee - m);
#pragma unroll
        for (int e = 0; e < 16; e++) {
            int s = __shfl(sv, e);
            float w = __shfl(wv, (hd << 4) + e);
            half4v hv = *(const half4v*)(hH + ((size_t)s << 8) + (lane << 2));
            a0 = fmaf(w, (float)hv[0], a0);
            a1 = fmaf(w, (float)hv[1], a1);
            a2 = fmaf(w, (float)hv[2], a2);
            a3 = fmaf(w, (float)hv[3], a3);
        }
    }
    if (i < s1) {
        int idx = i + g16;
        int sv = eSrc[(idx < s1) ? idx : (s1 - 1)];
        float ee = sin + sj[sv * HEADS + hd];
        ee = fmaxf(ee, SLOPE * ee);
        float wv = (idx < s1) ? __expf(ee - m) : 0.f;
        int rem = s1 - i;
        for (int e = 0; e < rem; e++) {
            int s = __shfl(sv, e);
            float w = __shfl(wv, (hd << 4) + e);
            half4v hv = *(const half4v*)(hH + ((size_t)s << 8) + (lane << 2));
            a0 = fmaf(w, (float)hv[0], a0);
            a1 = fmaf(w, (float)hv[1], a1);
            a2 = fmaf(w, (float)hv[2], a2);
            a3 = fmaf(w, (float)hv[3], a3);
        }
    }
    f32x4 o;
    o[0] = a0 * inv; o[1] = a1 * inv; o[2] = a2 * inv; o[3] = a3 * inv;
    if (ELU_OUT) {
#pragma unroll
        for (int e = 0; e < 4; e++) o[e] = (o[e] > 0.f) ? o[e] : expm1f(o[e]);
    }
    *(f32x4*)(out + ((size_t)n << 8) + (lane << 2)) = o;
}

// ---------------- final aggregate (layer 3): wave = node, all heads ----------------
// pass 1 as aggregate4; pass 2 gathers with lanes 0..39 (head lane/10) using
// shfl-broadcast weights; epilogue mean-over-heads + log_softmax wave-locally.
__global__ __launch_bounds__(256) void aggregate_final_kernel(
        const _Float16* __restrict__ hH,   // [N][160] fp16
        const float* __restrict__ si, const float* __restrict__ sj,
        const int* __restrict__ rowStart, const int* __restrict__ eSrc,
        float* __restrict__ out, int N) {
    const int NCLS = 40, D = 160;
    __shared__ float tmp[4][D];
    int wid = threadIdx.x >> 6;
    int n = blockIdx.x * 4 + wid;
    if (n >= N) return;
    int lane = threadIdx.x & 63;
    int hd1 = lane >> 4, g16 = lane & 15;
    int s0 = rowStart[n], s1 = rowStart[n + 1];
    float sin1 = si[n * HEADS + hd1];

    // ---- pass 1: per-head online (m, d) ----
    float m = -INFINITY, d = 0.f;
    for (int i = s0 + g16; i < s1; i += 16) {
        int s = eSrc[i];
        float e = sin1 + sj[s * HEADS + hd1];
        e = fmaxf(e, SLOPE * e);
        float nm = fmaxf(m, e);
        d = d * __expf(m - nm) + __expf(e - nm);
        m = nm;
    }
#pragma unroll
    for (int off = 8; off; off >>= 1) {
        float om = __shfl_xor(m, off);
        float od = __shfl_xor(d, off);
        float nm = fmaxf(m, om);
        float w1 = (m == -INFINITY) ? 0.f : __expf(m - nm);
        float w2 = (om == -INFINITY) ? 0.f : __expf(om - nm);
        d = d * w1 + od * w2;
        m = nm;
    }
    float inv = (d > 0.f) ? 1.f / d : 0.f;

    // pass-2 lane layout: lanes 0..39, head = lane/10, features 4*lane..4*lane+3
    int hd2 = (lane < NCLS) ? (lane / 10) : 3;
    float inv2 = __shfl(inv, hd2 << 4);

    // ---- pass 2 ----
    float a0 = 0.f, a1 = 0.f, a2 = 0.f, a3 = 0.f;
    int i = s0;
    for (; i + 16 <= s1; i += 16) {
        int sv = eSrc[i + g16];
        float ee = sin1 + sj[sv * HEADS + hd1];
        ee = fmaxf(ee, SLOPE * ee);
        float wv = __expf(ee - m);
#pragma unroll
        for (int e = 0; e < 16; e++) {
            int s = __shfl(sv, e);
            float w = __shfl(wv, (hd2 << 4) + e);
            if (lane < NCLS) {
                half4v hv = *(const half4v*)(hH + (size_t)s * D + (lane << 2));
                a0 = fmaf(w, (float)hv[0], a0);
                a1 = fmaf(w, (float)hv[1], a1);
                a2 = fmaf(w, (float)hv[2], a2);
                a3 = fmaf(w, (float)hv[3], a3);
            }
        }
    }
    if (i < s1) {
        int idx = i + g16;
        int sv = eSrc[(idx < s1) ? idx : (s1 - 1)];
        float ee = sin1 + sj[sv * HEADS + hd1];
        ee = fmaxf(ee, SLOPE * ee);
        float wv = (idx < s1) ? __expf(ee - m) : 0.f;
        int rem = s1 - i;
        for (int e = 0; e < rem; e++) {
            int s = __shfl(sv, e);
            float w = __shfl(wv, (hd2 << 4) + e);
            if (lane < NCLS) {
                half4v hv = *(const half4v*)(hH + (size_t)s * D + (lane << 2));
                a0 = fmaf(w, (float)hv[0], a0);
                a1 = fmaf(w, (float)hv[1], a1);
                a2 = fmaf(w, (float)hv[2], a2);
                a3 = fmaf(w, (float)hv[3], a3);
            }
        }
    }
    // ---- epilogue: mean over heads + log_softmax (wave-local) ----
    if (lane < NCLS) {
        tmp[wid][(lane << 2) + 0] = a0 * inv2;
        tmp[wid][(lane << 2) + 1] = a1 * inv2;
        tmp[wid][(lane << 2) + 2] = a2 * inv2;
        tmp[wid][(lane << 2) + 3] = a3 * inv2;
    }
    __builtin_amdgcn_wave_barrier();  // same wave: LDS writes then reads, in-order
    float x = -INFINITY;
    if (lane < NCLS)
        x = 0.25f * (tmp[wid][lane] + tmp[wid][NCLS + lane] +
                     tmp[wid][2 * NCLS + lane] + tmp[wid][3 * NCLS + lane]);
    float mx = x;
#pragma unroll
    for (int off = 32; off; off >>= 1) mx = fmaxf(mx, __shfl_xor(mx, off));
    float ex = (lane < NCLS) ? __expf(x - mx) : 0.f;
    float ssum = ex;
#pragma unroll
    for (int off = 32; off; off >>= 1) ssum += __shfl_xor(ssum, off);
    float ls = logf(ssum);
    if (lane < NCLS) out[(size_t)n * NCLS + lane] = (x - mx) - ls;
}

// ---------------- launch ----------------
extern "C" void kernel_launch(void* const* d_in, const int* in_sizes, int n_in,
                              void* d_out, int out_size, void* d_ws, size_t ws_size,
                              hipStream_t stream) {
    const float* x   = (const float*)d_in[0];
    const int*   ei  = (const int*)d_in[1];
    const float* W1  = (const float*)d_in[2];
    const float* ai1 = (const float*)d_in[3];
    const float* aj1 = (const float*)d_in[4];
    const float* W2  = (const float*)d_in[5];
    const float* ai2 = (const float*)d_in[6];
    const float* aj2 = (const float*)d_in[7];
    const float* W3  = (const float*)d_in[8];
    const float* ai3 = (const float*)d_in[9];
    const float* aj3 = (const float*)d_in[10];

    const int IN_F = 256, HID = 64, NCLS = 40;
    const int N = in_sizes[0] / IN_F;   // 50000
    const int E = in_sizes[1] / 2;      // 800000
    const int D1 = HEADS * HID;         // 256
    const int D3 = HEADS * NCLS;        // 160

    const int* eSrcIn = ei;
    const int* eDstIn = ei + E;

    char* p = (char*)d_ws;
    auto carve = [&](size_t bytes) {
        char* r = p;
        p += (bytes + 255) & ~(size_t)255;
        return r;
    };
    float*     hA        = (float*)carve((size_t)N * D1 * 4);
    _Float16*  hH        = (_Float16*)carve((size_t)N * D1 * 2);
    float*     si        = (float*)carve((size_t)N * HEADS * 4);
    float*     sj        = (float*)carve((size_t)N * HEADS * 4);
    int*       rowStart  = (int*)carve((size_t)(N + 1) * 4);
    int*       cursor    = (int*)carve((size_t)N * 4);
    int*       eSrc      = (int*)carve((size_t)E * 4);
    int*       blockSums = (int*)carve(1024);
    short*     W1hiT     = (short*)carve((size_t)IN_F * D1 * 2);
    short*     W1loT     = (short*)carve((size_t)IN_F * D1 * 2);
    short*     W2hiT     = (short*)carve((size_t)D1 * D1 * 2);
    short*     W2loT     = (short*)carve((size_t)D1 * D1 * 2);
    short*     W3hiT     = (short*)carve((size_t)D1 * D3 * 2);
    short*     W3loT     = (short*)carve((size_t)D1 * D3 * 2);

    int nbScan = cdiv(N, 256);

    // ---- W prep ----
    wsplit_kernel<<<cdiv(IN_F * D1, 256), 256, 0, stream>>>(W1, W1hiT, W1loT, IN_F, D1);
    wsplit_kernel<<<cdiv(D1 * D1, 256), 256, 0, stream>>>(W2, W2hiT, W2loT, D1, D1);
    wsplit_kernel<<<cdiv(D1 * D3, 256), 256, 0, stream>>>(W3, W3hiT, W3loT, D1, D3);

    // ---- CSR build ----
    hipMemsetAsync(cursor, 0, (size_t)N * 4, stream);
    hist_kernel<<<cdiv(E, 256), 256, 0, stream>>>(eDstIn, cursor, E);
    scan1_kernel<<<nbScan, 256, 0, stream>>>(cursor, rowStart, blockSums, N);
    scan2_kernel<<<1, 256, 0, stream>>>(blockSums, nbScan);
    scan3_kernel<<<cdiv(N + 1, 256), 256, 0, stream>>>(rowStart, blockSums, N, E);
    hipMemsetAsync(cursor, 0, (size_t)N * 4, stream);
    scatter_kernel<<<cdiv(E, 256), 256, 0, stream>>>(eSrcIn, eDstIn, rowStart, cursor, eSrc, E);

    dim3 g1(cdiv(D1, 64), cdiv(N, 128));
    dim3 g3(cdiv(D3, 64), cdiv(N, 128));
    int nb4 = cdiv(N, 4);

    // ---- layer 1 ----
    gemm_mfma_kernel<<<g1, 256, 0, stream>>>(x, W1hiT, W1loT, hH, N, IN_F, D1);
    score16_kernel<64><<<nb4, 256, 0, stream>>>(hH, ai1, aj1, si, sj, N);
    aggregate4_kernel<true><<<nb4, 256, 0, stream>>>(hH, si, sj, rowStart, eSrc, hA, N);

    // ---- layer 2 ----
    gemm_mfma_kernel<<<g1, 256, 0, stream>>>(hA, W2hiT, W2loT, hH, N, D1, D1);
    score16_kernel<64><<<nb4, 256, 0, stream>>>(hH, ai2, aj2, si, sj, N);
    aggregate4_kernel<true><<<nb4, 256, 0, stream>>>(hH, si, sj, rowStart, eSrc, hA, N);

    // ---- layer 3 ----
    gemm_mfma_kernel<<<g3, 256, 0, stream>>>(hA, W3hiT, W3loT, hH, N, D1, D3);
    score16_kernel<40><<<nb4, 256, 0, stream>>>(hH, ai3, aj3, si, sj, N);
    aggregate_final_kernel<<<nb4, 256, 0, stream>>>(hH, si, sj, rowStart, eSrc, (float*)d_out, N);
}

// Round 9
// 588.591 us; speedup vs baseline: 1.8942x; 1.0083x over previous
//
#include <hip/hip_runtime.h>
#include <math.h>

// GAT 3-layer forward on MI355X.
//   xsplit: x fp32 -> (hi,lo) bf16 planes (done once)
//   W-prep: split each W into (hi,lo) bf16, transpose to [n][k]
//   CSR build (histogram -> scan -> scatter by dst)
//   L1..L3: gemm_pre (3x bf16-split MFMA, pre-split inputs, reg-prefetch,
//           writes fp16 h) -> score16 -> aggregate
// Aggregates: wave = node (all 4 heads), fp16 batched gather, shfl-broadcast
// weights; epilogue writes next layer's A as bf16 hi/lo planes. No atomics.

#define HEADS 4
#define SLOPE 0.2f

typedef __attribute__((ext_vector_type(4))) float  f32x4;
typedef __attribute__((ext_vector_type(4))) short  short4v;
typedef __attribute__((ext_vector_type(8))) short  short8v;
typedef __attribute__((ext_vector_type(4))) _Float16 half4v;

static inline int cdiv(int a, int b) { return (a + b - 1) / b; }

// fp32 -> bf16 hi (truncate) + bf16 lo (truncate of exact remainder).
__device__ inline void split_bf16(float x, short& hi, short& lo) {
    unsigned b = __float_as_uint(x);
    hi = (short)(b >> 16);
    float hif = __uint_as_float(b & 0xffff0000u);
    float rem = x - hif;  // exact
    lo = (short)(__float_as_uint(rem) >> 16);
}

// ---------------- CSR build ----------------
__global__ void hist_kernel(const int* __restrict__ dst, int* __restrict__ cnt, int E) {
    int i = blockIdx.x * blockDim.x + threadIdx.x;
    if (i < E) atomicAdd(&cnt[dst[i]], 1);
}

__global__ void scan1_kernel(const int* __restrict__ cnt, int* __restrict__ rowStart,
                             int* __restrict__ blockSums, int N) {
    __shared__ int s[256];
    int t = threadIdx.x;
    int i = blockIdx.x * 256 + t;
    int v = (i < N) ? cnt[i] : 0;
    s[t] = v;
    for (int off = 1; off < 256; off <<= 1) {
        __syncthreads();
        int add = (t >= off) ? s[t - off] : 0;
        __syncthreads();
        s[t] += add;
    }
    __syncthreads();
    if (i < N) rowStart[i] = s[t] - v;
    if (t == 255) blockSums[blockIdx.x] = s[255];
}

__global__ void scan2_kernel(int* blockSums, int nb) {
    __shared__ int s[256];
    int t = threadIdx.x;
    int v = (t < nb) ? blockSums[t] : 0;
    s[t] = v;
    for (int off = 1; off < 256; off <<= 1) {
        __syncthreads();
        int add = (t >= off) ? s[t - off] : 0;
        __syncthreads();
        s[t] += add;
    }
    if (t < nb) blockSums[t] = s[t] - v;
}

__global__ void scan3_kernel(int* rowStart, const int* __restrict__ blockSums, int N, int E) {
    int i = blockIdx.x * 256 + threadIdx.x;
    if (i < N) rowStart[i] += blockSums[i >> 8];
    else if (i == N) rowStart[N] = E;
}

__global__ void scatter_kernel(const int* __restrict__ src, const int* __restrict__ dst,
                               const int* __restrict__ rowStart, int* __restrict__ cursor,
                               int* __restrict__ eSrc, int E) {
    int i = blockIdx.x * blockDim.x + threadIdx.x;
    if (i < E) {
        int d = dst[i];
        int pos = rowStart[d] + atomicAdd(&cursor[d], 1);
        eSrc[pos] = src[i];
    }
}

// ---------------- input split: fp32 -> hi/lo bf16 planes ----------------
__global__ void xsplit_kernel(const float* __restrict__ X, short* __restrict__ Hi,
                              short* __restrict__ Lo, int total4) {
    int q = blockIdx.x * 256 + threadIdx.x;
    if (q >= total4) return;
    f32x4 v = *(const f32x4*)(X + (size_t)q * 4);
    short4v h4, l4;
#pragma unroll
    for (int e = 0; e < 4; e++) {
        short hh, ll;
        split_bf16(v[e], hh, ll);
        h4[e] = hh;
        l4[e] = ll;
    }
    *(short4v*)(Hi + (size_t)q * 4) = h4;
    *(short4v*)(Lo + (size_t)q * 4) = l4;
}

// ---------------- W prep: split + transpose ----------------
__global__ void wsplit_kernel(const float* __restrict__ W, short* __restrict__ hiT,
                              short* __restrict__ loT, int K, int Nn) {
    int id = blockIdx.x * 256 + threadIdx.x;
    if (id >= K * Nn) return;
    int k = id / Nn, n = id - k * Nn;
    short h, l;
    split_bf16(W[id], h, l);
    hiT[n * K + k] = h;
    loT[n * K + k] = l;
}

// ---------------- MFMA GEMM (pre-split): Ch = fp16(A @ W) ----------------
// A given as hi/lo bf16 planes [M][K]; W as hi/lo [n][k] planes.
// 3x bf16-split MFMA (hi*hi + hi*lo + lo*hi), fp32 acc, fp16 out.
// Tile 128x64, BK=32, 256 thr = 4 waves (2x2). Register prefetch of tile k+1.
__global__ __launch_bounds__(256) void gemm_pre_kernel(
        const short* __restrict__ AHi, const short* __restrict__ ALo,
        const short* __restrict__ BhiT, const short* __restrict__ BloT,
        _Float16* __restrict__ Ch, int M, int K, int Nn) {
    __shared__ short Ahi[128 * 40];
    __shared__ short Alo[128 * 40];
    __shared__ short Bhi[64 * 40];
    __shared__ short Blo[64 * 40];
    int t = threadIdx.x;
    int lane = t & 63, wid = t >> 6;
    int wr = wid >> 1, wc = wid & 1;
    int l15 = lane & 15, g = lane >> 4;
    int row0 = blockIdx.y * 128, col0 = blockIdx.x * 64;

    // A-stage geometry: idx = t + c*256 in [0,512): r = idx>>2, kq = idx&3
    int ar[2], akq[2];
#pragma unroll
    for (int c = 0; c < 2; c++) {
        int idx = t + c * 256;
        ar[c] = idx >> 2;
        akq[c] = idx & 3;
    }
    // B-stage geometry: n = t>>2, kq = t&3
    int bn = t >> 2, bkq = t & 3;
    int bgc = col0 + bn;

    short8v rAh[2], rAl[2], rBh, rBl;

    auto stage_load = [&](int k0) {
#pragma unroll
        for (int c = 0; c < 2; c++) {
            int gr = row0 + ar[c];
            if (gr < M) {
                size_t off = (size_t)gr * K + k0 + akq[c] * 8;
                rAh[c] = *(const short8v*)(AHi + off);
                rAl[c] = *(const short8v*)(ALo + off);
            } else {
                rAh[c] = (short8v){};
                rAl[c] = (short8v){};
            }
        }
        if (bgc < Nn) {
            size_t off = (size_t)bgc * K + k0 + bkq * 8;
            rBh = *(const short8v*)(BhiT + off);
            rBl = *(const short8v*)(BloT + off);
        } else {
            rBh = (short8v){};
            rBl = (short8v){};
        }
    };
    auto stage_store = [&]() {
#pragma unroll
        for (int c = 0; c < 2; c++) {
            *(short8v*)(Ahi + ar[c] * 40 + akq[c] * 8) = rAh[c];
            *(short8v*)(Alo + ar[c] * 40 + akq[c] * 8) = rAl[c];
        }
        *(short8v*)(Bhi + bn * 40 + bkq * 8) = rBh;
        *(short8v*)(Blo + bn * 40 + bkq * 8) = rBl;
    };

    f32x4 acc[4][2] = {};

    stage_load(0);
    stage_store();
    __syncthreads();

    for (int k0 = 0; k0 < K; k0 += 32) {
        bool more = (k0 + 32 < K);
        if (more) stage_load(k0 + 32);

        short8v ah[4], al[4], bh[2], bl[2];
#pragma unroll
        for (int mt = 0; mt < 4; mt++) {
            int r = wr * 64 + mt * 16 + l15;
            ah[mt] = *(const short8v*)(Ahi + r * 40 + g * 8);
            al[mt] = *(const short8v*)(Alo + r * 40 + g * 8);
        }
#pragma unroll
        for (int nt = 0; nt < 2; nt++) {
            int n = wc * 32 + nt * 16 + l15;
            bh[nt] = *(const short8v*)(Bhi + n * 40 + g * 8);
            bl[nt] = *(const short8v*)(Blo + n * 40 + g * 8);
        }
#pragma unroll
        for (int mt = 0; mt < 4; mt++)
#pragma unroll
            for (int nt = 0; nt < 2; nt++) {
                acc[mt][nt] = __builtin_amdgcn_mfma_f32_16x16x32_bf16(ah[mt], bh[nt], acc[mt][nt], 0, 0, 0);
                acc[mt][nt] = __builtin_amdgcn_mfma_f32_16x16x32_bf16(ah[mt], bl[nt], acc[mt][nt], 0, 0, 0);
                acc[mt][nt] = __builtin_amdgcn_mfma_f32_16x16x32_bf16(al[mt], bh[nt], acc[mt][nt], 0, 0, 0);
            }
        __syncthreads();
        if (more) {
            stage_store();
            __syncthreads();
        }
    }
#pragma unroll
    for (int mt = 0; mt < 4; mt++) {
        int rbase = row0 + wr * 64 + mt * 16 + g * 4;
#pragma unroll
        for (int nt = 0; nt < 2; nt++) {
            int gc = col0 + wc * 32 + nt * 16 + l15;
            if (gc >= Nn) continue;
#pragma unroll
            for (int r = 0; r < 4; r++) {
                int gr = rbase + r;
                if (gr < M) Ch[(size_t)gr * Nn + gc] = (_Float16)acc[mt][nt][r];
            }
        }
    }
}

// ---------------- attention scores from fp16 h: si/sj [N,H] ----------------
template <int F>
__global__ __launch_bounds__(256) void score16_kernel(
        const _Float16* __restrict__ hH, const float* __restrict__ attI,
        const float* __restrict__ attJ, float* __restrict__ si,
        float* __restrict__ sj, int N) {
    const int D = HEADS * F;
    int wid = threadIdx.x >> 6;
    int n = blockIdx.x * 4 + wid;
    if (n >= N) return;
    int lane = threadIdx.x & 63;
    int hd = lane >> 4, g16 = lane & 15;
    float v1 = 0.f, v2 = 0.f;
    if (g16 * 4 < F) {
        half4v hv = *(const half4v*)(hH + (size_t)n * D + hd * F + g16 * 4);
        f32x4 ai = *(const f32x4*)(attI + hd * F + g16 * 4);
        f32x4 aj = *(const f32x4*)(attJ + hd * F + g16 * 4);
#pragma unroll
        for (int e = 0; e < 4; e++) {
            float xv = (float)hv[e];
            v1 = fmaf(xv, ai[e], v1);
            v2 = fmaf(xv, aj[e], v2);
        }
    }
#pragma unroll
    for (int off = 8; off; off >>= 1) {
        v1 += __shfl_xor(v1, off);
        v2 += __shfl_xor(v2, off);
    }
    if (g16 == 0) {
        si[n * HEADS + hd] = v1;
        sj[n * HEADS + hd] = v2;
    }
}

// ---------------- aggregate (layers 1&2, F=64): wave = node ----------------
// pass 1: per-head online (m,d) on 16-lane groups.
// pass 2: 16-edge batches; weights computed once per (edge,head) lane and
// shfl-broadcast; fp16x4 gathers. Epilogue: ELU, split to bf16 hi/lo planes.
__global__ __launch_bounds__(256) void aggregate4_kernel(
        const _Float16* __restrict__ hH,   // [N][256] fp16
        const float* __restrict__ si, const float* __restrict__ sj,
        const int* __restrict__ rowStart, const int* __restrict__ eSrc,
        short* __restrict__ outHi, short* __restrict__ outLo, int N) {
    int wid = threadIdx.x >> 6;
    int n = blockIdx.x * 4 + wid;
    if (n >= N) return;
    int lane = threadIdx.x & 63;
    int hd = lane >> 4, g16 = lane & 15;
    int s0 = rowStart[n], s1 = rowStart[n + 1];
    float sin = si[n * HEADS + hd];

    // ---- pass 1: per-head online (m, d) over 16-lane group ----
    float m = -INFINITY, d = 0.f;
    for (int i = s0 + g16; i < s1; i += 16) {
        int s = eSrc[i];
        float e = sin + sj[s * HEADS + hd];
        e = fmaxf(e, SLOPE * e);
        float nm = fmaxf(m, e);
        d = d * __expf(m - nm) + __expf(e - nm);
        m = nm;
    }
#pragma unroll
    for (int off = 8; off; off >>= 1) {
        float om = __shfl_xor(m, off);
        float od = __shfl_xor(d, off);
        float nm = fmaxf(m, om);
        float w1 = (m == -INFINITY) ? 0.f : __expf(m - nm);
        float w2 = (om == -INFINITY) ? 0.f : __expf(om - nm);
        d = d * w1 + od * w2;
        m = nm;
    }
    float inv = (d > 0.f) ? 1.f / d : 0.f;

    // ---- pass 2 ----
    float a0 = 0.f, a1 = 0.f, a2 = 0.f, a3 = 0.f;
    int i = s0;
    for (; i + 16 <= s1; i += 16) {
        int sv = eSrc[i + g16];
        float ee = sin + sj[sv * HEADS + hd];
        ee = fmaxf(ee, SLOPE * ee);
        float wv = __expf(ee - m);
#pragma unroll
        for (int e = 0; e < 16; e++) {
            int s = __shfl(sv, e);
            float w = __shfl(wv, (hd << 4) + e);
            half4v hv = *(const half4v*)(hH + ((size_t)s << 8) + (lane << 2));
            a0 = fmaf(w, (float)hv[0], a0);
            a1 = fmaf(w, (float)hv[1], a1);
            a2 = fmaf(w, (float)hv[2], a2);
            a3 = fmaf(w, (float)hv[3], a3);
        }
    }
    if (i < s1) {
        int idx = i + g16;
        int sv = eSrc[(idx < s1) ? idx : (s1 - 1)];
        float ee = sin + sj[sv * HEADS + hd];
        ee = fmaxf(ee, SLOPE * ee);
        float wv = (idx < s1) ? __expf(ee - m) : 0.f;
        int rem = s1 - i;
        for (int e = 0; e < rem; e++) {
            int s = __shfl(sv, e);
            float w = __shfl(wv, (hd << 4) + e);
            half4v hv = *(const half4v*)(hH + ((size_t)s << 8) + (lane << 2));
            a0 = fmaf(w, (float)hv[0], a0);
            a1 = fmaf(w, (float)hv[1], a1);
            a2 = fmaf(w, (float)hv[2], a2);
            a3 = fmaf(w, (float)hv[3], a3);
        }
    }
    f32x4 o;
    o[0] = a0 * inv; o[1] = a1 * inv; o[2] = a2 * inv; o[3] = a3 * inv;
    short4v h4, l4;
#pragma unroll
    for (int e = 0; e < 4; e++) {
        float v = o[e];
        v = (v > 0.f) ? v : expm1f(v);   // ELU
        short hh, ll;
        split_bf16(v, hh, ll);
        h4[e] = hh;
        l4[e] = ll;
    }
    *(short4v*)(outHi + ((size_t)n << 8) + (lane << 2)) = h4;
    *(short4v*)(outLo + ((size_t)n << 8) + (lane << 2)) = l4;
}

// ---------------- final aggregate (layer 3): wave = node, all heads ----------------
__global__ __launch_bounds__(256) void aggregate_final_kernel(
        const _Float16* __restrict__ hH,   // [N][160] fp16
        const float* __restrict__ si, const float* __restrict__ sj,
        const int* __restrict__ rowStart, const int* __restrict__ eSrc,
        float* __restrict__ out, int N) {
    const int NCLS = 40, D = 160;
    __shared__ float tmp[4][D];
    int wid = threadIdx.x >> 6;
    int n = blockIdx.x * 4 + wid;
    if (n >= N) return;
    int lane = threadIdx.x & 63;
    int hd1 = lane >> 4, g16 = lane & 15;
    int s0 = rowStart[n], s1 = rowStart[n + 1];
    float sin1 = si[n * HEADS + hd1];

    float m = -INFINITY, d = 0.f;
    for (int i = s0 + g16; i < s1; i += 16) {
        int s = eSrc[i];
        float e = sin1 + sj[s * HEADS + hd1];
        e = fmaxf(e, SLOPE * e);
        float nm = fmaxf(m, e);
        d = d * __expf(m - nm) + __expf(e - nm);
        m = nm;
    }
#pragma unroll
    for (int off = 8; off; off >>= 1) {
        float om = __shfl_xor(m, off);
        float od = __shfl_xor(d, off);
        float nm = fmaxf(m, om);
        float w1 = (m == -INFINITY) ? 0.f : __expf(m - nm);
        float w2 = (om == -INFINITY) ? 0.f : __expf(om - nm);
        d = d * w1 + od * w2;
        m = nm;
    }
    float inv = (d > 0.f) ? 1.f / d : 0.f;

    int hd2 = (lane < NCLS) ? (lane / 10) : 3;
    float inv2 = __shfl(inv, hd2 << 4);

    float a0 = 0.f, a1 = 0.f, a2 = 0.f, a3 = 0.f;
    int i = s0;
    for (; i + 16 <= s1; i += 16) {
        int sv = eSrc[i + g16];
        float ee = sin1 + sj[sv * HEADS + hd1];
        ee = fmaxf(ee, SLOPE * ee);
        float wv = __expf(ee - m);
#pragma unroll
        for (int e = 0; e < 16; e++) {
            int s = __shfl(sv, e);
            float w = __shfl(wv, (hd2 << 4) + e);
            if (lane < NCLS) {
                half4v hv = *(const half4v*)(hH + (size_t)s * D + (lane << 2));
                a0 = fmaf(w, (float)hv[0], a0);
                a1 = fmaf(w, (float)hv[1], a1);
                a2 = fmaf(w, (float)hv[2], a2);
                a3 = fmaf(w, (float)hv[3], a3);
            }
        }
    }
    if (i < s1) {
        int idx = i + g16;
        int sv = eSrc[(idx < s1) ? idx : (s1 - 1)];
        float ee = sin1 + sj[sv * HEADS + hd1];
        ee = fmaxf(ee, SLOPE * ee);
        float wv = (idx < s1) ? __expf(ee - m) : 0.f;
        int rem = s1 - i;
        for (int e = 0; e < rem; e++) {
            int s = __shfl(sv, e);
            float w = __shfl(wv, (hd2 << 4) + e);
            if (lane < NCLS) {
                half4v hv = *(const half4v*)(hH + (size_t)s * D + (lane << 2));
                a0 = fmaf(w, (float)hv[0], a0);
                a1 = fmaf(w, (float)hv[1], a1);
                a2 = fmaf(w, (float)hv[2], a2);
                a3 = fmaf(w, (float)hv[3], a3);
            }
        }
    }
    if (lane < NCLS) {
        tmp[wid][(lane << 2) + 0] = a0 * inv2;
        tmp[wid][(lane << 2) + 1] = a1 * inv2;
        tmp[wid][(lane << 2) + 2] = a2 * inv2;
        tmp[wid][(lane << 2) + 3] = a3 * inv2;
    }
    __builtin_amdgcn_wave_barrier();  // same wave: LDS writes then reads, in-order
    float x = -INFINITY;
    if (lane < NCLS)
        x = 0.25f * (tmp[wid][lane] + tmp[wid][NCLS + lane] +
                     tmp[wid][2 * NCLS + lane] + tmp[wid][3 * NCLS + lane]);
    float mx = x;
#pragma unroll
    for (int off = 32; off; off >>= 1) mx = fmaxf(mx, __shfl_xor(mx, off));
    float ex = (lane < NCLS) ? __expf(x - mx) : 0.f;
    float ssum = ex;
#pragma unroll
    for (int off = 32; off; off >>= 1) ssum += __shfl_xor(ssum, off);
    float ls = logf(ssum);
    if (lane < NCLS) out[(size_t)n * NCLS + lane] = (x - mx) - ls;
}

// ---------------- launch ----------------
extern "C" void kernel_launch(void* const* d_in, const int* in_sizes, int n_in,
                              void* d_out, int out_size, void* d_ws, size_t ws_size,
                              hipStream_t stream) {
    const float* x   = (const float*)d_in[0];
    const int*   ei  = (const int*)d_in[1];
    const float* W1  = (const float*)d_in[2];
    const float* ai1 = (const float*)d_in[3];
    const float* aj1 = (const float*)d_in[4];
    const float* W2  = (const float*)d_in[5];
    const float* ai2 = (const float*)d_in[6];
    const float* aj2 = (const float*)d_in[7];
    const float* W3  = (const float*)d_in[8];
    const float* ai3 = (const float*)d_in[9];
    const float* aj3 = (const float*)d_in[10];

    const int IN_F = 256, NCLS = 40;
    const int N = in_sizes[0] / IN_F;   // 50000
    const int E = in_sizes[1] / 2;      // 800000
    const int D1 = HEADS * 64;          // 256
    const int D3 = HEADS * NCLS;        // 160

    const int* eSrcIn = ei;
    const int* eDstIn = ei + E;

    char* p = (char*)d_ws;
    auto carve = [&](size_t bytes) {
        char* r = p;
        p += (bytes + 255) & ~(size_t)255;
        return r;
    };
    short*     xHi       = (short*)carve((size_t)N * IN_F * 2);
    short*     xLo       = (short*)carve((size_t)N * IN_F * 2);
    short*     aHi       = (short*)carve((size_t)N * D1 * 2);
    short*     aLo       = (short*)carve((size_t)N * D1 * 2);
    _Float16*  hH        = (_Float16*)carve((size_t)N * D1 * 2);
    float*     si        = (float*)carve((size_t)N * HEADS * 4);
    float*     sj        = (float*)carve((size_t)N * HEADS * 4);
    int*       rowStart  = (int*)carve((size_t)(N + 1) * 4);
    int*       cursor    = (int*)carve((size_t)N * 4);
    int*       eSrc      = (int*)carve((size_t)E * 4);
    int*       blockSums = (int*)carve(1024);
    short*     W1hiT     = (short*)carve((size_t)IN_F * D1 * 2);
    short*     W1loT     = (short*)carve((size_t)IN_F * D1 * 2);
    short*     W2hiT     = (short*)carve((size_t)D1 * D1 * 2);
    short*     W2loT     = (short*)carve((size_t)D1 * D1 * 2);
    short*     W3hiT     = (short*)carve((size_t)D1 * D3 * 2);
    short*     W3loT     = (short*)carve((size_t)D1 * D3 * 2);

    int nbScan = cdiv(N, 256);

    // ---- input + W prep ----
    xsplit_kernel<<<cdiv(N * IN_F / 4, 256), 256, 0, stream>>>(x, xHi, xLo, N * IN_F / 4);
    wsplit_kernel<<<cdiv(IN_F * D1, 256), 256, 0, stream>>>(W1, W1hiT, W1loT, IN_F, D1);
    wsplit_kernel<<<cdiv(D1 * D1, 256), 256, 0, stream>>>(W2, W2hiT, W2loT, D1, D1);
    wsplit_kernel<<<cdiv(D1 * D3, 256), 256, 0, stream>>>(W3, W3hiT, W3loT, D1, D3);

    // ---- CSR build ----
    hipMemsetAsync(cursor, 0, (size_t)N * 4, stream);
    hist_kernel<<<cdiv(E, 256), 256, 0, stream>>>(eDstIn, cursor, E);
    scan1_kernel<<<nbScan, 256, 0, stream>>>(cursor, rowStart, blockSums, N);
    scan2_kernel<<<1, 256, 0, stream>>>(blockSums, nbScan);
    scan3_kernel<<<cdiv(N + 1, 256), 256, 0, stream>>>(rowStart, blockSums, N, E);
    hipMemsetAsync(cursor, 0, (size_t)N * 4, stream);
    scatter_kernel<<<cdiv(E, 256), 256, 0, stream>>>(eSrcIn, eDstIn, rowStart, cursor, eSrc, E);

    dim3 g1(cdiv(D1, 64), cdiv(N, 128));
    dim3 g3(cdiv(D3, 64), cdiv(N, 128));
    int nb4 = cdiv(N, 4);

    // ---- layer 1 ----
    gemm_pre_kernel<<<g1, 256, 0, stream>>>(xHi, xLo, W1hiT, W1loT, hH, N, IN_F, D1);
    score16_kernel<64><<<nb4, 256, 0, stream>>>(hH, ai1, aj1, si, sj, N);
    aggregate4_kernel<<<nb4, 256, 0, stream>>>(hH, si, sj, rowStart, eSrc, aHi, aLo, N);

    // ---- layer 2 ----
    gemm_pre_kernel<<<g1, 256, 0, stream>>>(aHi, aLo, W2hiT, W2loT, hH, N, D1, D1);
    score16_kernel<64><<<nb4, 256, 0, stream>>>(hH, ai2, aj2, si, sj, N);
    aggregate4_kernel<<<nb4, 256, 0, stream>>>(hH, si, sj, rowStart, eSrc, aHi, aLo, N);

    // ---- layer 3 ----
    gemm_pre_kernel<<<g3, 256, 0, stream>>>(aHi, aLo, W3hiT, W3loT, hH, N, D1, D3);
    score16_kernel<40><<<nb4, 256, 0, stream>>>(hH, ai3, aj3, si, sj, N);
    aggregate_final_kernel<<<nb4, 256, 0, stream>>>(hH, si, sj, rowStart, eSrc, (float*)d_out, N);
}

// Round 11
// 575.564 us; speedup vs baseline: 1.9371x; 1.0226x over previous
//
#include <hip/hip_runtime.h>
#include <math.h>

// GAT 3-layer forward on MI355X.
//   xsplit: x fp32 -> (hi,lo) bf16 planes (once)
//   W-prep: split each W into (hi,lo) bf16, transpose to [n][k]
//   CSR build (histogram -> scan -> scatter by dst)
//   L1/L2: gemm_wide (BN=256 full-width: A read ONCE, W L2-resident) -> score16 -> aggregate4
//   L3:    gemm_pre (BN=64) -> score16 -> aggregate_final
// Aggregates: wave = node (all 4 heads), fp16 gather with SGPR-uniform src base
// (readlane) + shfl-broadcast weights. No atomics in hot path.

#define HEADS 4
#define SLOPE 0.2f

typedef __attribute__((ext_vector_type(4))) float  f32x4;
typedef __attribute__((ext_vector_type(4))) short  short4v;
typedef __attribute__((ext_vector_type(8))) short  short8v;
typedef __attribute__((ext_vector_type(4))) _Float16 half4v;

static inline int cdiv(int a, int b) { return (a + b - 1) / b; }

// fp32 -> bf16 hi (truncate) + bf16 lo (truncate of exact remainder).
__device__ inline void split_bf16(float x, short& hi, short& lo) {
    unsigned b = __float_as_uint(x);
    hi = (short)(b >> 16);
    float hif = __uint_as_float(b & 0xffff0000u);
    float rem = x - hif;  // exact
    lo = (short)(__float_as_uint(rem) >> 16);
}

// ---------------- CSR build ----------------
__global__ void hist_kernel(const int* __restrict__ dst, int* __restrict__ cnt, int E) {
    int i = blockIdx.x * blockDim.x + threadIdx.x;
    if (i < E) atomicAdd(&cnt[dst[i]], 1);
}

__global__ void scan1_kernel(const int* __restrict__ cnt, int* __restrict__ rowStart,
                             int* __restrict__ blockSums, int N) {
    __shared__ int s[256];
    int t = threadIdx.x;
    int i = blockIdx.x * 256 + t;
    int v = (i < N) ? cnt[i] : 0;
    s[t] = v;
    for (int off = 1; off < 256; off <<= 1) {
        __syncthreads();
        int add = (t >= off) ? s[t - off] : 0;
        __syncthreads();
        s[t] += add;
    }
    __syncthreads();
    if (i < N) rowStart[i] = s[t] - v;
    if (t == 255) blockSums[blockIdx.x] = s[255];
}

__global__ void scan2_kernel(int* blockSums, int nb) {
    __shared__ int s[256];
    int t = threadIdx.x;
    int v = (t < nb) ? blockSums[t] : 0;
    s[t] = v;
    for (int off = 1; off < 256; off <<= 1) {
        __syncthreads();
        int add = (t >= off) ? s[t - off] : 0;
        __syncthreads();
        s[t] += add;
    }
    if (t < nb) blockSums[t] = s[t] - v;
}

__global__ void scan3_kernel(int* rowStart, const int* __restrict__ blockSums, int N, int E) {
    int i = blockIdx.x * 256 + threadIdx.x;
    if (i < N) rowStart[i] += blockSums[i >> 8];
    else if (i == N) rowStart[N] = E;
}

__global__ void scatter_kernel(const int* __restrict__ src, const int* __restrict__ dst,
                               const int* __restrict__ rowStart, int* __restrict__ cursor,
                               int* __restrict__ eSrc, int E) {
    int i = blockIdx.x * blockDim.x + threadIdx.x;
    if (i < E) {
        int d = dst[i];
        int pos = rowStart[d] + atomicAdd(&cursor[d], 1);
        eSrc[pos] = src[i];
    }
}

// ---------------- input split: fp32 -> hi/lo bf16 planes ----------------
__global__ void xsplit_kernel(const float* __restrict__ X, short* __restrict__ Hi,
                              short* __restrict__ Lo, int total4) {
    int q = blockIdx.x * 256 + threadIdx.x;
    if (q >= total4) return;
    f32x4 v = *(const f32x4*)(X + (size_t)q * 4);
    short4v h4, l4;
#pragma unroll
    for (int e = 0; e < 4; e++) {
        short hh, ll;
        split_bf16(v[e], hh, ll);
        h4[e] = hh;
        l4[e] = ll;
    }
    *(short4v*)(Hi + (size_t)q * 4) = h4;
    *(short4v*)(Lo + (size_t)q * 4) = l4;
}

// ---------------- W prep: split + transpose ----------------
__global__ void wsplit_kernel(const float* __restrict__ W, short* __restrict__ hiT,
                              short* __restrict__ loT, int K, int Nn) {
    int id = blockIdx.x * 256 + threadIdx.x;
    if (id >= K * Nn) return;
    int k = id / Nn, n = id - k * Nn;
    short h, l;
    split_bf16(W[id], h, l);
    hiT[n * K + k] = h;
    loT[n * K + k] = l;
}

// ---------------- wide MFMA GEMM (L1/L2): Ch[M,256] = fp16(A @ W) ----------------
// BM=128, BN=256 (full width -> A read once; W stays L2-hot).
// 4 waves (2x2): wave = 64 rows x 128 cols; acc[4][8] f32x4 = 128 VGPR.
__global__ __launch_bounds__(256) void gemm_wide_kernel(
        const short* __restrict__ AHi, const short* __restrict__ ALo,
        const short* __restrict__ BhiT, const short* __restrict__ BloT,
        _Float16* __restrict__ Ch, int M, int K) {
    const int Nn = 256;
    __shared__ short Ahi[128 * 40];
    __shared__ short Alo[128 * 40];
    __shared__ short Bhi[256 * 40];
    __shared__ short Blo[256 * 40];
    int t = threadIdx.x;
    int lane = t & 63, wid = t >> 6;
    int wr = wid >> 1, wc = wid & 1;
    int l15 = lane & 15, g = lane >> 4;
    int row0 = blockIdx.x * 128;

    short8v rAh[2], rAl[2], rBh[4], rBl[4];

    auto stage_load = [&](int k0) {
#pragma unroll
        for (int c = 0; c < 2; c++) {
            int idx = t + c * 256;
            int r = idx >> 2, kq = idx & 3;
            int gr = row0 + r;
            if (gr < M) {
                size_t off = (size_t)gr * K + k0 + kq * 8;
                rAh[c] = *(const short8v*)(AHi + off);
                rAl[c] = *(const short8v*)(ALo + off);
            } else {
                rAh[c] = (short8v){};
                rAl[c] = (short8v){};
            }
        }
#pragma unroll
        for (int c = 0; c < 4; c++) {
            int idx = t + c * 256;
            int n = idx >> 2, kq = idx & 3;
            size_t off = (size_t)n * K + k0 + kq * 8;
            rBh[c] = *(const short8v*)(BhiT + off);
            rBl[c] = *(const short8v*)(BloT + off);
        }
    };
    auto stage_store = [&]() {
#pragma unroll
        for (int c = 0; c < 2; c++) {
            int idx = t + c * 256;
            int r = idx >> 2, kq = idx & 3;
            *(short8v*)(Ahi + r * 40 + kq * 8) = rAh[c];
            *(short8v*)(Alo + r * 40 + kq * 8) = rAl[c];
        }
#pragma unroll
        for (int c = 0; c < 4; c++) {
            int idx = t + c * 256;
            int n = idx >> 2, kq = idx & 3;
            *(short8v*)(Bhi + n * 40 + kq * 8) = rBh[c];
            *(short8v*)(Blo + n * 40 + kq * 8) = rBl[c];
        }
    };

    f32x4 acc[4][8] = {};

    stage_load(0);
    stage_store();
    __syncthreads();

    for (int k0 = 0; k0 < K; k0 += 32) {
        bool more = (k0 + 32 < K);
        if (more) stage_load(k0 + 32);

        short8v ah[4], al[4];
#pragma unroll
        for (int mt = 0; mt < 4; mt++) {
            int r = wr * 64 + mt * 16 + l15;
            ah[mt] = *(const short8v*)(Ahi + r * 40 + g * 8);
            al[mt] = *(const short8v*)(Alo + r * 40 + g * 8);
        }
#pragma unroll
        for (int nc = 0; nc < 8; nc++) {
            int n = wc * 128 + nc * 16 + l15;
            short8v bh = *(const short8v*)(Bhi + n * 40 + g * 8);
            short8v bl = *(const short8v*)(Blo + n * 40 + g * 8);
#pragma unroll
            for (int mt = 0; mt < 4; mt++) {
                acc[mt][nc] = __builtin_amdgcn_mfma_f32_16x16x32_bf16(ah[mt], bh, acc[mt][nc], 0, 0, 0);
                acc[mt][nc] = __builtin_amdgcn_mfma_f32_16x16x32_bf16(ah[mt], bl, acc[mt][nc], 0, 0, 0);
                acc[mt][nc] = __builtin_amdgcn_mfma_f32_16x16x32_bf16(al[mt], bh, acc[mt][nc], 0, 0, 0);
            }
        }
        __syncthreads();
        if (more) {
            stage_store();
            __syncthreads();
        }
    }
#pragma unroll
    for (int mt = 0; mt < 4; mt++) {
        int rbase = row0 + wr * 64 + mt * 16 + g * 4;
#pragma unroll
        for (int nc = 0; nc < 8; nc++) {
            int gc = wc * 128 + nc * 16 + l15;
#pragma unroll
            for (int r = 0; r < 4; r++) {
                int gr = rbase + r;
                if (gr < M) Ch[(size_t)gr * Nn + gc] = (_Float16)acc[mt][nc][r];
            }
        }
    }
}

// ---------------- MFMA GEMM (L3, pre-split, BN=64): Ch = fp16(A @ W) ----------------
__global__ __launch_bounds__(256) void gemm_pre_kernel(
        const short* __restrict__ AHi, const short* __restrict__ ALo,
        const short* __restrict__ BhiT, const short* __restrict__ BloT,
        _Float16* __restrict__ Ch, int M, int K, int Nn) {
    __shared__ short Ahi[128 * 40];
    __shared__ short Alo[128 * 40];
    __shared__ short Bhi[64 * 40];
    __shared__ short Blo[64 * 40];
    int t = threadIdx.x;
    int lane = t & 63, wid = t >> 6;
    int wr = wid >> 1, wc = wid & 1;
    int l15 = lane & 15, g = lane >> 4;
    int row0 = blockIdx.y * 128, col0 = blockIdx.x * 64;

    int ar[2], akq[2];
#pragma unroll
    for (int c = 0; c < 2; c++) {
        int idx = t + c * 256;
        ar[c] = idx >> 2;
        akq[c] = idx & 3;
    }
    int bn = t >> 2, bkq = t & 3;
    int bgc = col0 + bn;

    short8v rAh[2], rAl[2], rBh, rBl;

    auto stage_load = [&](int k0) {
#pragma unroll
        for (int c = 0; c < 2; c++) {
            int gr = row0 + ar[c];
            if (gr < M) {
                size_t off = (size_t)gr * K + k0 + akq[c] * 8;
                rAh[c] = *(const short8v*)(AHi + off);
                rAl[c] = *(const short8v*)(ALo + off);
            } else {
                rAh[c] = (short8v){};
                rAl[c] = (short8v){};
            }
        }
        if (bgc < Nn) {
            size_t off = (size_t)bgc * K + k0 + bkq * 8;
            rBh = *(const short8v*)(BhiT + off);
            rBl = *(const short8v*)(BloT + off);
        } else {
            rBh = (short8v){};
            rBl = (short8v){};
        }
    };
    auto stage_store = [&]() {
#pragma unroll
        for (int c = 0; c < 2; c++) {
            *(short8v*)(Ahi + ar[c] * 40 + akq[c] * 8) = rAh[c];
            *(short8v*)(Alo + ar[c] * 40 + akq[c] * 8) = rAl[c];
        }
        *(short8v*)(Bhi + bn * 40 + bkq * 8) = rBh;
        *(short8v*)(Blo + bn * 40 + bkq * 8) = rBl;
    };

    f32x4 acc[4][2] = {};

    stage_load(0);
    stage_store();
    __syncthreads();

    for (int k0 = 0; k0 < K; k0 += 32) {
        bool more = (k0 + 32 < K);
        if (more) stage_load(k0 + 32);

        short8v ah[4], al[4], bh[2], bl[2];
#pragma unroll
        for (int mt = 0; mt < 4; mt++) {
            int r = wr * 64 + mt * 16 + l15;
            ah[mt] = *(const short8v*)(Ahi + r * 40 + g * 8);
            al[mt] = *(const short8v*)(Alo + r * 40 + g * 8);
        }
#pragma unroll
        for (int nt = 0; nt < 2; nt++) {
            int n = wc * 32 + nt * 16 + l15;
            bh[nt] = *(const short8v*)(Bhi + n * 40 + g * 8);
            bl[nt] = *(const short8v*)(Blo + n * 40 + g * 8);
        }
#pragma unroll
        for (int mt = 0; mt < 4; mt++)
#pragma unroll
            for (int nt = 0; nt < 2; nt++) {
                acc[mt][nt] = __builtin_amdgcn_mfma_f32_16x16x32_bf16(ah[mt], bh[nt], acc[mt][nt], 0, 0, 0);
                acc[mt][nt] = __builtin_amdgcn_mfma_f32_16x16x32_bf16(ah[mt], bl[nt], acc[mt][nt], 0, 0, 0);
                acc[mt][nt] = __builtin_amdgcn_mfma_f32_16x16x32_bf16(al[mt], bh[nt], acc[mt][nt], 0, 0, 0);
            }
        __syncthreads();
        if (more) {
            stage_store();
            __syncthreads();
        }
    }
#pragma unroll
    for (int mt = 0; mt < 4; mt++) {
        int rbase = row0 + wr * 64 + mt * 16 + g * 4;
#pragma unroll
        for (int nt = 0; nt < 2; nt++) {
            int gc = col0 + wc * 32 + nt * 16 + l15;
            if (gc >= Nn) continue;
#pragma unroll
            for (int r = 0; r < 4; r++) {
                int gr = rbase + r;
                if (gr < M) Ch[(size_t)gr * Nn + gc] = (_Float16)acc[mt][nt][r];
            }
        }
    }
}

// ---------------- attention scores from fp16 h: si/sj [N,H] ----------------
template <int F>
__global__ __launch_bounds__(256) void score16_kernel(
        const _Float16* __restrict__ hH, const float* __restrict__ attI,
        const float* __restrict__ attJ, float* __restrict__ si,
        float* __restrict__ sj, int N) {
    const int D = HEADS * F;
    int wid = threadIdx.x >> 6;
    int n = blockIdx.x * 4 + wid;
    if (n >= N) return;
    int lane = threadIdx.x & 63;
    int hd = lane >> 4, g16 = lane & 15;
    float v1 = 0.f, v2 = 0.f;
    if (g16 * 4 < F) {
        half4v hv = *(const half4v*)(hH + (size_t)n * D + hd * F + g16 * 4);
        f32x4 ai = *(const f32x4*)(attI + hd * F + g16 * 4);
        f32x4 aj = *(const f32x4*)(attJ + hd * F + g16 * 4);
#pragma unroll
        for (int e = 0; e < 4; e++) {
            float xv = (float)hv[e];
            v1 = fmaf(xv, ai[e], v1);
            v2 = fmaf(xv, aj[e], v2);
        }
    }
#pragma unroll
    for (int off = 8; off; off >>= 1) {
        v1 += __shfl_xor(v1, off);
        v2 += __shfl_xor(v2, off);
    }
    if (g16 == 0) {
        si[n * HEADS + hd] = v1;
        sj[n * HEADS + hd] = v2;
    }
}

// ---------------- aggregate (layers 1&2, F=64): wave = node ----------------
// pass 1: per-head online (m,d) on 16-lane groups.
// pass 2: 16-edge batches; src index via readlane (SGPR-uniform base),
// weight via shfl; fp16x4 gathers. Epilogue: ELU + split to bf16 hi/lo.
__global__ __launch_bounds__(256) void aggregate4_kernel(
        const _Float16* __restrict__ hH,   // [N][256] fp16
        const float* __restrict__ si, const float* __restrict__ sj,
        const int* __restrict__ rowStart, const int* __restrict__ eSrc,
        short* __restrict__ outHi, short* __restrict__ outLo, int N) {
    int wid = threadIdx.x >> 6;
    int n = blockIdx.x * 4 + wid;
    if (n >= N) return;
    int lane = threadIdx.x & 63;
    int hd = lane >> 4, g16 = lane & 15;
    int s0 = rowStart[n], s1 = rowStart[n + 1];
    float sin = si[n * HEADS + hd];

    // ---- pass 1 ----
    float m = -INFINITY, d = 0.f;
    for (int i = s0 + g16; i < s1; i += 16) {
        int s = eSrc[i];
        float e = sin + sj[s * HEADS + hd];
        e = fmaxf(e, SLOPE * e);
        float nm = fmaxf(m, e);
        d = d * __expf(m - nm) + __expf(e - nm);
        m = nm;
    }
#pragma unroll
    for (int off = 8; off; off >>= 1) {
        float om = __shfl_xor(m, off);
        float od = __shfl_xor(d, off);
        float nm = fmaxf(m, om);
        float w1 = (m == -INFINITY) ? 0.f : __expf(m - nm);
        float w2 = (om == -INFINITY) ? 0.f : __expf(om - nm);
        d = d * w1 + od * w2;
        m = nm;
    }
    float inv = (d > 0.f) ? 1.f / d : 0.f;

    // ---- pass 2 ----
    float a0 = 0.f, a1 = 0.f, a2 = 0.f, a3 = 0.f;
    int laneoff = lane << 2;
    int i = s0;
    for (; i + 16 <= s1; i += 16) {
        int sv = eSrc[i + g16];   // lanes 0-15 == 16-31 == 32-47 == 48-63
        float ee = sin + sj[sv * HEADS + hd];
        ee = fmaxf(ee, SLOPE * ee);
        float wv = __expf(ee - m);
#pragma unroll
        for (int e = 0; e < 16; e++) {
            int s = __builtin_amdgcn_readlane(sv, e);   // SGPR-uniform
            float w = __shfl(wv, (hd << 4) + e);
            const _Float16* hp = hH + ((size_t)(unsigned)s << 8);
            half4v hv = *(const half4v*)(hp + laneoff);
            a0 = fmaf(w, (float)hv[0], a0);
            a1 = fmaf(w, (float)hv[1], a1);
            a2 = fmaf(w, (float)hv[2], a2);
            a3 = fmaf(w, (float)hv[3], a3);
        }
    }
    if (i < s1) {
        int idx = i + g16;
        int sv = eSrc[(idx < s1) ? idx : (s1 - 1)];
        float ee = sin + sj[sv * HEADS + hd];
        ee = fmaxf(ee, SLOPE * ee);
        float wv = (idx < s1) ? __expf(ee - m) : 0.f;
        int rem = s1 - i;
        for (int e = 0; e < rem; e++) {
            int s = __builtin_amdgcn_readlane(sv, e);   // e wave-uniform
            float w = __shfl(wv, (hd << 4) + e);
            const _Float16* hp = hH + ((size_t)(unsigned)s << 8);
            half4v hv = *(const half4v*)(hp + laneoff);
            a0 = fmaf(w, (float)hv[0], a0);
            a1 = fmaf(w, (float)hv[1], a1);
            a2 = fmaf(w, (float)hv[2], a2);
            a3 = fmaf(w, (float)hv[3], a3);
        }
    }
    f32x4 o;
    o[0] = a0 * inv; o[1] = a1 * inv; o[2] = a2 * inv; o[3] = a3 * inv;
    short4v h4, l4;
#pragma unroll
    for (int e = 0; e < 4; e++) {
        float v = o[e];
        v = (v > 0.f) ? v : expm1f(v);   // ELU
        short hh, ll;
        split_bf16(v, hh, ll);
        h4[e] = hh;
        l4[e] = ll;
    }
    *(short4v*)(outHi + ((size_t)n << 8) + laneoff) = h4;
    *(short4v*)(outLo + ((size_t)n << 8) + laneoff) = l4;
}

// ---------------- final aggregate (layer 3): wave = node, all heads ----------------
__global__ __launch_bounds__(256) void aggregate_final_kernel(
        const _Float16* __restrict__ hH,   // [N][160] fp16
        const float* __restrict__ si, const float* __restrict__ sj,
        const int* __restrict__ rowStart, const int* __restrict__ eSrc,
        float* __restrict__ out, int N) {
    const int NCLS = 40, D = 160;
    __shared__ float tmp[4][D];
    int wid = threadIdx.x >> 6;
    int n = blockIdx.x * 4 + wid;
    if (n >= N) return;
    int lane = threadIdx.x & 63;
    int hd1 = lane >> 4, g16 = lane & 15;
    int s0 = rowStart[n], s1 = rowStart[n + 1];
    float sin1 = si[n * HEADS + hd1];

    float m = -INFINITY, d = 0.f;
    for (int i = s0 + g16; i < s1; i += 16) {
        int s = eSrc[i];
        float e = sin1 + sj[s * HEADS + hd1];
        e = fmaxf(e, SLOPE * e);
        float nm = fmaxf(m, e);
        d = d * __expf(m - nm) + __expf(e - nm);
        m = nm;
    }
#pragma unroll
    for (int off = 8; off; off >>= 1) {
        float om = __shfl_xor(m, off);
        float od = __shfl_xor(d, off);
        float nm = fmaxf(m, om);
        float w1 = (m == -INFINITY) ? 0.f : __expf(m - nm);
        float w2 = (om == -INFINITY) ? 0.f : __expf(om - nm);
        d = d * w1 + od * w2;
        m = nm;
    }
    float inv = (d > 0.f) ? 1.f / d : 0.f;

    int hd2 = (lane < NCLS) ? (lane / 10) : 3;
    float inv2 = __shfl(inv, hd2 << 4);

    float a0 = 0.f, a1 = 0.f, a2 = 0.f, a3 = 0.f;
    int laneoff = lane << 2;
    int i = s0;
    for (; i + 16 <= s1; i += 16) {
        int sv = eSrc[i + g16];
        float ee = sin1 + sj[sv * HEADS + hd1];
        ee = fmaxf(ee, SLOPE * ee);
        float wv = __expf(ee - m);
#pragma unroll
        for (int e = 0; e < 16; e++) {
            int s = __builtin_amdgcn_readlane(sv, e);
            float w = __shfl(wv, (hd2 << 4) + e);
            if (lane < NCLS) {
                const _Float16* hp = hH + (size_t)(unsigned)s * D;
                half4v hv = *(const half4v*)(hp + laneoff);
                a0 = fmaf(w, (float)hv[0], a0);
                a1 = fmaf(w, (float)hv[1], a1);
                a2 = fmaf(w, (float)hv[2], a2);
                a3 = fmaf(w, (float)hv[3], a3);
            }
        }
    }
    if (i < s1) {
        int idx = i + g16;
        int sv = eSrc[(idx < s1) ? idx : (s1 - 1)];
        float ee = sin1 + sj[sv * HEADS + hd1];
        ee = fmaxf(ee, SLOPE * ee);
        float wv = (idx < s1) ? __expf(ee - m) : 0.f;
        int rem = s1 - i;
        for (int e = 0; e < rem; e++) {
            int s = __builtin_amdgcn_readlane(sv, e);
            float w = __shfl(wv, (hd2 << 4) + e);
            if (lane < NCLS) {
                const _Float16* hp = hH + (size_t)(unsigned)s * D;
                half4v hv = *(const half4v*)(hp + laneoff);
                a0 = fmaf(w, (float)hv[0], a0);
                a1 = fmaf(w, (float)hv[1], a1);
                a2 = fmaf(w, (float)hv[2], a2);
                a3 = fmaf(w, (float)hv[3], a3);
            }
        }
    }
    if (lane < NCLS) {
        tmp[wid][laneoff + 0] = a0 * inv2;
        tmp[wid][laneoff + 1] = a1 * inv2;
        tmp[wid][laneoff + 2] = a2 * inv2;
        tmp[wid][laneoff + 3] = a3 * inv2;
    }
    __builtin_amdgcn_wave_barrier();  // same wave: LDS writes then reads, in-order
    float x = -INFINITY;
    if (lane < NCLS)
        x = 0.25f * (tmp[wid][lane] + tmp[wid][NCLS + lane] +
                     tmp[wid][2 * NCLS + lane] + tmp[wid][3 * NCLS + lane]);
    float mx = x;
#pragma unroll
    for (int off = 32; off; off >>= 1) mx = fmaxf(mx, __shfl_xor(mx, off));
    float ex = (lane < NCLS) ? __expf(x - mx) : 0.f;
    float ssum = ex;
#pragma unroll
    for (int off = 32; off; off >>= 1) ssum += __shfl_xor(ssum, off);
    float ls = logf(ssum);
    if (lane < NCLS) out[(size_t)n * NCLS + lane] = (x - mx) - ls;
}

// ---------------- launch ----------------
extern "C" void kernel_launch(void* const* d_in, const int* in_sizes, int n_in,
                              void* d_out, int out_size, void* d_ws, size_t ws_size,
                              hipStream_t stream) {
    const float* x   = (const float*)d_in[0];
    const int*   ei  = (const int*)d_in[1];
    const float* W1  = (const float*)d_in[2];
    const float* ai1 = (const float*)d_in[3];
    const float* aj1 = (const float*)d_in[4];
    const float* W2  = (const float*)d_in[5];
    const float* ai2 = (const float*)d_in[6];
    const float* aj2 = (const float*)d_in[7];
    const float* W3  = (const float*)d_in[8];
    const float* ai3 = (const float*)d_in[9];
    const float* aj3 = (const float*)d_in[10];

    const int IN_F = 256, NCLS = 40;
    const int N = in_sizes[0] / IN_F;   // 50000
    const int E = in_sizes[1] / 2;      // 800000
    const int D1 = HEADS * 64;          // 256
    const int D3 = HEADS * NCLS;        // 160

    const int* eSrcIn = ei;
    const int* eDstIn = ei + E;

    char* p = (char*)d_ws;
    auto carve = [&](size_t bytes) {
        char* r = p;
        p += (bytes + 255) & ~(size_t)255;
        return r;
    };
    short*     xHi       = (short*)carve((size_t)N * IN_F * 2);
    short*     xLo       = (short*)carve((size_t)N * IN_F * 2);
    short*     aHi       = (short*)carve((size_t)N * D1 * 2);
    short*     aLo       = (short*)carve((size_t)N * D1 * 2);
    _Float16*  hH        = (_Float16*)carve((size_t)N * D1 * 2);
    float*     si        = (float*)carve((size_t)N * HEADS * 4);
    float*     sj        = (float*)carve((size_t)N * HEADS * 4);
    int*       rowStart  = (int*)carve((size_t)(N + 1) * 4);
    int*       cursor    = (int*)carve((size_t)N * 4);
    int*       eSrc      = (int*)carve((size_t)E * 4);
    int*       blockSums = (int*)carve(1024);
    short*     W1hiT     = (short*)carve((size_t)IN_F * D1 * 2);
    short*     W1loT     = (short*)carve((size_t)IN_F * D1 * 2);
    short*     W2hiT     = (short*)carve((size_t)D1 * D1 * 2);
    short*     W2loT     = (short*)carve((size_t)D1 * D1 * 2);
    short*     W3hiT     = (short*)carve((size_t)D1 * D3 * 2);
    short*     W3loT     = (short*)carve((size_t)D1 * D3 * 2);

    int nbScan = cdiv(N, 256);

    // ---- input + W prep ----
    xsplit_kernel<<<cdiv(N * IN_F / 4, 256), 256, 0, stream>>>(x, xHi, xLo, N * IN_F / 4);
    wsplit_kernel<<<cdiv(IN_F * D1, 256), 256, 0, stream>>>(W1, W1hiT, W1loT, IN_F, D1);
    wsplit_kernel<<<cdiv(D1 * D1, 256), 256, 0, stream>>>(W2, W2hiT, W2loT, D1, D1);
    wsplit_kernel<<<cdiv(D1 * D3, 256), 256, 0, stream>>>(W3, W3hiT, W3loT, D1, D3);

    // ---- CSR build ----
    hipMemsetAsync(cursor, 0, (size_t)N * 4, stream);
    hist_kernel<<<cdiv(E, 256), 256, 0, stream>>>(eDstIn, cursor, E);
    scan1_kernel<<<nbScan, 256, 0, stream>>>(cursor, rowStart, blockSums, N);
    scan2_kernel<<<1, 256, 0, stream>>>(blockSums, nbScan);
    scan3_kernel<<<cdiv(N + 1, 256), 256, 0, stream>>>(rowStart, blockSums, N, E);
    hipMemsetAsync(cursor, 0, (size_t)N * 4, stream);
    scatter_kernel<<<cdiv(E, 256), 256, 0, stream>>>(eSrcIn, eDstIn, rowStart, cursor, eSrc, E);

    int nbRow = cdiv(N, 128);
    dim3 g3(cdiv(D3, 64), nbRow);
    int nb4 = cdiv(N, 4);

    // ---- layer 1 ----
    gemm_wide_kernel<<<nbRow, 256, 0, stream>>>(xHi, xLo, W1hiT, W1loT, hH, N, IN_F);
    score16_kernel<64><<<nb4, 256, 0, stream>>>(hH, ai1, aj1, si, sj, N);
    aggregate4_kernel<<<nb4, 256, 0, stream>>>(hH, si, sj, rowStart, eSrc, aHi, aLo, N);

    // ---- layer 2 ----
    gemm_wide_kernel<<<nbRow, 256, 0, stream>>>(aHi, aLo, W2hiT, W2loT, hH, N, D1);
    score16_kernel<64><<<nb4, 256, 0, stream>>>(hH, ai2, aj2, si, sj, N);
    aggregate4_kernel<<<nb4, 256, 0, stream>>>(hH, si, sj, rowStart, eSrc, aHi, aLo, N);

    // ---- layer 3 ----
    gemm_pre_kernel<<<g3, 256, 0, stream>>>(aHi, aLo, W3hiT, W3loT, hH, N, D1, D3);
    score16_kernel<40><<<nb4, 256, 0, stream>>>(hH, ai3, aj3, si, sj, N);
    aggregate_final_kernel<<<nb4, 256, 0, stream>>>(hH, si, sj, rowStart, eSrc, (float*)d_out, N);
}